// Round 19
// baseline (241.005 us; speedup 1.0000x reference)
//
#include <hip/hip_runtime.h>
#include <cstdint>
#include <cstddef>

#define D_MODEL 1024
#define N_HEADS 16
#define INNER   1024
#define NBATCH  4
#define SEQ     2048
#define MTOT    (NBATCH * SEQ)   // 8192
#define LOG2E   1.44269504088896f
#define BSTRIDE 4352             // biasG per-head stride
#define MASKC   1442.695041f

typedef _Float16 f16;
typedef __attribute__((ext_vector_type(8))) _Float16 f16x8;
typedef __attribute__((ext_vector_type(4))) _Float16 f16x4;
typedef __attribute__((ext_vector_type(2))) _Float16 f16x2;
typedef __attribute__((ext_vector_type(2))) __fp16   h16x2;
typedef __attribute__((ext_vector_type(4))) float    f32x4;

// packed f32->f16 convert (RTZ) shim
__device__ __forceinline__ f16x2 cvtpk(float x, float y) {
#if __has_builtin(__builtin_amdgcn_cvt_pkrtz)
  h16x2 r = __builtin_amdgcn_cvt_pkrtz(x, y);
  return __builtin_bit_cast(f16x2, r);
#else
  f16x2 r; r[0] = (f16)x; r[1] = (f16)y; return r;
#endif
}

// ---------------------------------------------------------------- f32 -> f16
__global__ void k_cvt(const float* __restrict__ src, f16* __restrict__ dst, int n4, float scale) {
  int i = blockIdx.x * 256 + threadIdx.x;
  if (i < n4) {
    const float4 v = reinterpret_cast<const float4*>(src)[i];
    f16x4 h;
    h[0] = (f16)(v.x * scale); h[1] = (f16)(v.y * scale);
    h[2] = (f16)(v.z * scale); h[3] = (f16)(v.w * scale);
    reinterpret_cast<f16x4*>(dst)[i] = h;
  }
}

// fused weight converts: blockIdx.y selects {wq(scaled), wk, wv, wo}
__global__ void k_cvtw(const float* __restrict__ wq, const float* __restrict__ wk,
                       const float* __restrict__ wv, const float* __restrict__ wo,
                       f16* __restrict__ dq, f16* __restrict__ dk,
                       f16* __restrict__ dv, f16* __restrict__ dwo) {
  const int y = blockIdx.y;
  const float* src = y == 0 ? wq : (y == 1 ? wk : (y == 2 ? wv : wo));
  f16* dst = y == 0 ? dq : (y == 1 ? dk : (y == 2 ? dv : dwo));
  const float scale = y == 0 ? LOG2E : 1.0f;
  const int i = blockIdx.x * 256 + threadIdx.x;
  const float4 v = reinterpret_cast<const float4*>(src)[i];
  f16x4 h;
  h[0] = (f16)(v.x * scale); h[1] = (f16)(v.y * scale);
  h[2] = (f16)(v.z * scale); h[3] = (f16)(v.w * scale);
  reinterpret_cast<f16x4*>(dst)[i] = h;
}

// ------------------------------------------------- T5 relative bias, 1-D delta table
__global__ void k_bias(const float* __restrict__ relb, float* __restrict__ biasG) {
  const int i = blockIdx.x * 256 + threadIdx.x;  // 0..4351
  const int h = blockIdx.y;
  const int d = i - 2048;
  const int sgn = d > 0 ? 16 : 0;
  const int a = d < 0 ? -d : d;
  int bucket;
  if (a < 8) {
    bucket = a;
  } else {
    float t = logf((float)a / 8.0f);
    t = t / 2.772588722239781f;   // ln(16)
    t = t * 8.0f;
    int lg = 8 + (int)t;
    bucket = lg < 15 ? lg : 15;
  }
  biasG[h * BSTRIDE + i] = relb[(sgn + bucket) * N_HEADS + h] * LOG2E - MASKC;
}

// ------------------------------------------------- async global->LDS (16B)
__device__ __forceinline__ void gload_lds16(const void* g, void* l) {
  __builtin_amdgcn_global_load_lds(
      (const __attribute__((address_space(1))) unsigned int*)g,
      (__attribute__((address_space(3))) unsigned int*)l,
      16, 0, 0);
}

// ------------------------------------------------- C = A * W^T  (f16 in, K=1024)
// MODE 0: f16 row-major; MODE 1: f32 row-major; MODE 2: Vt interleaved.
template <int MODE>
__device__ __forceinline__ void gemm_body(const f16* __restrict__ A,
                                          const f16* __restrict__ W,
                                          void* __restrict__ Cp,
                                          int m0, int n0) {
  __shared__ __align__(16) f16 As[128 * 64];
  __shared__ __align__(16) f16 Bs[128 * 64];
  const int t = threadIdx.x;
  const int lane = t & 63;
  const int wid = t >> 6;
  const int wr = wid >> 1;
  const int wc = wid & 1;
  const int g = lane >> 4;
  const int lr = lane & 15;

  f32x4 acc[4][4] = {};
  const char* Ab = (const char*)A;
  const char* Wb = (const char*)W;

  for (int kt = 0; kt < D_MODEL / 64; ++kt) {
    const int k0 = kt * 64;
    __syncthreads();
#pragma unroll
    for (int i = 0; i < 4; ++i) {
      const int idx = i * 256 + t;
      const int row = idx >> 3;
      const int cb  = (idx & 7) * 16;
      gload_lds16(Ab + ((size_t)(m0 + row) * D_MODEL + k0) * 2 + cb, (char*)As + idx * 16);
      gload_lds16(Wb + ((size_t)(n0 + row) * D_MODEL + k0) * 2 + cb, (char*)Bs + idx * 16);
    }
    asm volatile("s_waitcnt vmcnt(0)" ::: "memory");
    __syncthreads();

    f16x8 af[4][2], bf[4][2];
#pragma unroll
    for (int mi = 0; mi < 4; ++mi)
#pragma unroll
      for (int kk = 0; kk < 2; ++kk)
        af[mi][kk] = *(const f16x8*)&As[(wr * 64 + mi * 16 + lr) * 64 + kk * 32 + g * 8];
#pragma unroll
    for (int ni = 0; ni < 4; ++ni)
#pragma unroll
      for (int kk = 0; kk < 2; ++kk)
        bf[ni][kk] = *(const f16x8*)&Bs[(wc * 64 + ni * 16 + lr) * 64 + kk * 32 + g * 8];
#pragma unroll
    for (int kk = 0; kk < 2; ++kk)
#pragma unroll
      for (int mi = 0; mi < 4; ++mi)
#pragma unroll
        for (int ni = 0; ni < 4; ++ni)
          acc[mi][ni] = __builtin_amdgcn_mfma_f32_16x16x32_f16(af[mi][kk], bf[ni][kk], acc[mi][ni], 0, 0, 0);
  }

#pragma unroll
  for (int mi = 0; mi < 4; ++mi)
#pragma unroll
    for (int ni = 0; ni < 4; ++ni) {
      const int n = n0 + wc * 64 + ni * 16 + lr;
      if (MODE == 2) {
        const int mbase = m0 + wr * 64 + mi * 16 + g * 4;   // s2, multiple of 4
        const int b2 = mbase >> 11, s2 = mbase & (SEQ - 1);
        const int h2 = n >> 6, d2 = n & 63;
        const int sub = ((s2 & 15) >> 2) * 8 + ((s2 >> 4) & 1) * 4;
        f16x4 w;
#pragma unroll
        for (int r = 0; r < 4; ++r) w[r] = (f16)acc[mi][ni][r];
        *(f16x4*)((f16*)Cp + ((size_t)((b2 * 16 + h2) * 64 + d2) * SEQ + (s2 >> 5) * 32 + sub)) = w;
      } else {
#pragma unroll
        for (int r = 0; r < 4; ++r) {
          const int m = m0 + wr * 64 + mi * 16 + g * 4 + r;
          if (MODE == 1)
            ((float*)Cp)[(size_t)m * INNER + n] = acc[mi][ni][r];
          else
            ((f16*)Cp)[(size_t)m * INNER + n] = (f16)acc[mi][ni][r];
        }
      }
    }
}

// 1D grid 1536, XCD-swizzled: all 8 n-tiles of one (z,y) A-panel on one XCD.
__global__ __launch_bounds__(256) void k_gemm_qkv(
    const f16* __restrict__ A,
    const f16* __restrict__ Wq, const f16* __restrict__ Wk, const f16* __restrict__ Wv,
    f16* __restrict__ Cq, f16* __restrict__ Ck, f16* __restrict__ Vt) {
  const int bid = (int)blockIdx.x;
  const int X = bid & 7, l = bid >> 3;     // X = xcd, l = 0..191
  const int zy = X * 24 + (l >> 3);        // 0..191
  const int x = l & 7;
  const int z = zy >> 6, y = zy & 63;
  if (z == 0)      gemm_body<0>(A, Wq, Cq, y * 128, x * 128);
  else if (z == 1) gemm_body<0>(A, Wk, Ck, y * 128, x * 128);
  else             gemm_body<2>(A, Wv, Vt, y * 128, x * 128);
}

// 1D grid 512, XCD-swizzled similarly.
__global__ __launch_bounds__(256) void k_gemm_out(
    const f16* __restrict__ A, const f16* __restrict__ W, float* __restrict__ C) {
  const int bid = (int)blockIdx.x;
  const int X = bid & 7, l = bid >> 3;     // l 0..63
  const int y = X * 8 + (l >> 3), x = l & 7;
  gemm_body<1>(A, W, C, y * 128, x * 128);
}

// ------------------------------------------------- flash attention
// Round-16 structure (best verified: 107.6us): block = 8 waves x 32 q =
// 256 q-rows, one (b,h), KVBLK=32, 2-phase LDS double-buffer, quad-parity
// bias (3x ds_read_b128/iter), setprio around MFMA clusters, mask fast path.
// Deltas vs round 16: (a) lsum via ones-row PV MFMA (drops 8 dot2/iter and
// the epilogue shuffles); (b) launch_bounds(512,2) — occupancy is grid- and
// LDS-capped at 2 blocks/CU, so the relaxed bound only prevents spill.
__global__ __launch_bounds__(512, 2) void k_attn(
    const f16* __restrict__ Q, const f16* __restrict__ K, const f16* __restrict__ Vt,
    const float* __restrict__ biasG, const float* __restrict__ mask,
    f16* __restrict__ ctx) {
  __shared__ __align__(16) float biasQ[4 * 2308]; // 4 parity copies, 36928 B
  __shared__ __align__(16) f16 Ks[2 * 2048];      // [k][d] swz bits 4-6, 4KB/buf
  __shared__ __align__(16) f16 Vs[2 * 2048];      // [d][32k interleaved] swz 4-5
  __shared__ int mflag;

  // XCD-aware remap: all 8 q-chunks of one (b,h) on one XCD; 8 bh per XCD.
  const int nb = (int)blockIdx.x;
  const int v = (nb & 7) * 64 + (nb >> 3);
  const int bh = v >> 3, qc = v & 7;
  const int b = bh >> 4, h = bh & 15;

  const int t = threadIdx.x, lane = t & 63, wid = t >> 6;  // wid 0..7
  const int g = lane >> 4, lr = lane & 15;
  const int qb = qc * 256;

  const float* maskB = mask + (size_t)b * SEQ;
  {
    // window w[j] = biasG[h][2048 + (j - (qb+255))]; copy c slot m = w[4m+c ..+3]
    const float* bgh = biasG + (size_t)h * BSTRIDE + (1793 - qb);
    for (int idx = t; idx < 4 * 576; idx += 512) {
      const int c = idx / 576, m = idx - c * 576;
      const int src = 4 * m + c;
      float4 w;
      w.x = bgh[src]; w.y = bgh[src + 1]; w.z = bgh[src + 2]; w.w = bgh[src + 3];
      *(float4*)&biasQ[c * 2308 + 4 * m] = w;
    }
  }
  if (t == 0) mflag = 1;
  __syncthreads();
  {
    bool bad = false;
    for (int i = t; i < SEQ; i += 512) bad |= (maskB[i] != 1.0f);
    if (bad) mflag = 0;
  }

  const char* Kg = (const char*)K + ((size_t)(b * SEQ) * INNER + h * 64) * 2;
  const char* Vg = (const char*)Vt + ((size_t)bh * 64) * SEQ * 2;

  // staging roles (wave-uniform split): t<256 -> K chunk, t>=256 -> V chunk
  const bool isK = t < 256;
  const int ts = t & 255;
  const int krow = ts >> 3, kch = ts & 7;
  const int vrow = ts >> 2, vch = ts & 3;
  const int stsrc = isK ? ((kch * 16) ^ ((krow & 7) << 4))
                        : ((vch * 16) ^ ((vrow & 3) << 4));

  const int qw = qb + wid * 32;

  f16x8 qa[2][2];
#pragma unroll
  for (int hh = 0; hh < 2; ++hh)
#pragma unroll
    for (int kk = 0; kk < 2; ++kk)
      qa[hh][kk] = *(const f16x8*)&Q[(size_t)(b * SEQ + qw + hh * 16 + lr) * INNER + h * 64 + kk * 32 + g * 8];

  // hoisted per-lane LDS byte offsets (loop-invariant)
  int koffs[2][2], voffs[4];
#pragma unroll
  for (int s = 0; s < 2; ++s)
#pragma unroll
    for (int hf = 0; hf < 2; ++hf)
      koffs[s][hf] = (s * 16 + lr) * 128 + ((hf * 64 + g * 16) ^ ((lr & 7) << 4));
#pragma unroll
  for (int dn = 0; dn < 4; ++dn)
    voffs[dn] = (dn * 16 + lr) * 64 + ((g * 16) ^ ((lr & 3) << 4));

  f32x4 o[2][4] = {};
  f32x4 o_l[2] = {};                         // ones-row PV accumulator = lsum
  float mrun[2] = {-__builtin_inff(), -__builtin_inff()};
  const f16x8 ones8 = {(f16)1, (f16)1, (f16)1, (f16)1, (f16)1, (f16)1, (f16)1, (f16)1};

  // quad-parity bias base: j0(K0) = K0 + jb2; quads at j0, j0+16, j0+32.
  const int jbase = 255 + 4 * g - wid * 32 - lr;
  const int jb2 = jbase - 16;
  const char* bqPtr = (const char*)biasQ
                      + (size_t)((jb2 & 3) * 2308 + ((jb2 >> 2) << 2)) * 4;

  // prologue: stage tile 0 into buf 0 (one 16B chunk per thread)
  if (isK)
    gload_lds16(Kg + ((size_t)krow * INNER) * 2 + stsrc, (char*)Ks + ts * 16);
  else
    gload_lds16(Vg + ((size_t)vrow * SEQ) * 2 + stsrc,   (char*)Vs + ts * 16);
  asm volatile("s_waitcnt vmcnt(0)" ::: "memory");
  __syncthreads();
  const bool useMask = (mflag == 0);

#define ATTN_ITER(BUF, K0, MK)                                                 \
  {                                                                            \
    float4 mk0 = {}, mk1 = {};                                                 \
    if (MK) {                                                                  \
      mk0 = *(const float4*)(maskB + (K0) + 4 * g);                            \
      mk1 = *(const float4*)(maskB + (K0) + 16 + 4 * g);                       \
    }                                                                          \
    const int k0n_ = ((K0) + 32 < SEQ) ? (K0) + 32 : 0;                        \
    if (isK)                                                                   \
      gload_lds16(Kg + ((size_t)(k0n_ + krow) * INNER) * 2 + stsrc,            \
                  (char*)Ks + ((BUF) ^ 1) * 4096 + ts * 16);                   \
    else                                                                       \
      gload_lds16(Vg + ((size_t)vrow * SEQ + k0n_) * 2 + stsrc,                \
                  (char*)Vs + ((BUF) ^ 1) * 4096 + ts * 16);                   \
    const f32x4 bq0 = *(const f32x4*)(bqPtr + (K0) * 4);                       \
    const f32x4 bq1 = *(const f32x4*)(bqPtr + (K0) * 4 + 64);                  \
    const f32x4 bq2 = *(const f32x4*)(bqPtr + (K0) * 4 + 128);                 \
    f16x8 kf[2][2];                                                            \
    _Pragma("unroll") for (int s = 0; s < 2; ++s)                              \
      _Pragma("unroll") for (int hf = 0; hf < 2; ++hf)                         \
        kf[s][hf] = *(const f16x8*)((const char*)Ks + (BUF) * 4096 + koffs[s][hf]); \
    f16x8 vv[4];                                                               \
    _Pragma("unroll") for (int dn = 0; dn < 4; ++dn)                           \
      vv[dn] = *(const f16x8*)((const char*)Vs + (BUF) * 4096 + voffs[dn]);    \
    f32x4 sg[2][2];                                                            \
    __builtin_amdgcn_s_setprio(1);                                             \
    _Pragma("unroll") for (int hh = 0; hh < 2; ++hh)                           \
      _Pragma("unroll") for (int s = 0; s < 2; ++s) {                          \
        const f32x4 bq = hh ? (s ? bq1 : bq0) : (s ? bq2 : bq1);               \
        f32x4 z;                                                               \
        if (MK) {                                                              \
          const float* mkp = (s == 0) ? (const float*)&mk0 : (const float*)&mk1; \
          _Pragma("unroll") for (int r = 0; r < 4; ++r)                        \
            z[r] = fmaf(mkp[r], MASKC, bq[r]);                                 \
        } else {                                                               \
          z = bq;                                                              \
        }                                                                      \
        z = __builtin_amdgcn_mfma_f32_16x16x32_f16(kf[s][0], qa[hh][0], z, 0, 0, 0); \
        z = __builtin_amdgcn_mfma_f32_16x16x32_f16(kf[s][1], qa[hh][1], z, 0, 0, 0); \
        sg[hh][s] = z;                                                         \
      }                                                                        \
    __builtin_amdgcn_s_setprio(0);                                             \
    float mxA = fmaxf(fmaxf(fmaxf(sg[0][0][0], sg[0][0][1]), fmaxf(sg[0][0][2], sg[0][0][3])), \
                      fmaxf(fmaxf(sg[0][1][0], sg[0][1][1]), fmaxf(sg[0][1][2], sg[0][1][3]))); \
    float mxB = fmaxf(fmaxf(fmaxf(sg[1][0][0], sg[1][0][1]), fmaxf(sg[1][0][2], sg[1][0][3])), \
                      fmaxf(fmaxf(sg[1][1][0], sg[1][1][1]), fmaxf(sg[1][1][2], sg[1][1][3]))); \
    if (__any((mxA > mrun[0] + 11.5415603f) || (mxB > mrun[1] + 11.5415603f))) { \
      mxA = fmaxf(mxA, __shfl_xor(mxA, 16));                                   \
      mxB = fmaxf(mxB, __shfl_xor(mxB, 16));                                   \
      mxA = fmaxf(mxA, __shfl_xor(mxA, 32));                                   \
      mxB = fmaxf(mxB, __shfl_xor(mxB, 32));                                   \
      const float mnA = fmaxf(mrun[0], mxA), mnB = fmaxf(mrun[1], mxB);        \
      const float aA = __builtin_amdgcn_exp2f(mrun[0] - mnA);                  \
      const float aB = __builtin_amdgcn_exp2f(mrun[1] - mnB);                  \
      _Pragma("unroll") for (int r = 0; r < 4; ++r) {                          \
        o_l[0][r] *= aA; o_l[1][r] *= aB;                                      \
      }                                                                        \
      _Pragma("unroll") for (int dn = 0; dn < 4; ++dn)                         \
        _Pragma("unroll") for (int r = 0; r < 4; ++r) {                        \
          o[0][dn][r] *= aA; o[1][dn][r] *= aB;                                \
        }                                                                      \
      mrun[0] = mnA; mrun[1] = mnB;                                            \
    }                                                                          \
    f16x8 pfA8, pfB8;                                                          \
    _Pragma("unroll") for (int s = 0; s < 2; ++s) {                            \
      float eA[4], eB[4];                                                      \
      _Pragma("unroll") for (int r = 0; r < 4; ++r) {                          \
        eA[r] = __builtin_amdgcn_exp2f(sg[0][s][r] - mrun[0]);                 \
        eB[r] = __builtin_amdgcn_exp2f(sg[1][s][r] - mrun[1]);                 \
      }                                                                        \
      const f16x2 a0 = cvtpk(eA[0], eA[1]), a1 = cvtpk(eA[2], eA[3]);          \
      const f16x2 b0 = cvtpk(eB[0], eB[1]), b1 = cvtpk(eB[2], eB[3]);          \
      pfA8[s * 4 + 0] = a0[0]; pfA8[s * 4 + 1] = a0[1];                        \
      pfA8[s * 4 + 2] = a1[0]; pfA8[s * 4 + 3] = a1[1];                        \
      pfB8[s * 4 + 0] = b0[0]; pfB8[s * 4 + 1] = b0[1];                        \
      pfB8[s * 4 + 2] = b1[0]; pfB8[s * 4 + 3] = b1[1];                        \
    }                                                                          \
    __builtin_amdgcn_s_setprio(1);                                             \
    _Pragma("unroll") for (int dn = 0; dn < 4; ++dn) {                         \
      o[0][dn] = __builtin_amdgcn_mfma_f32_16x16x32_f16(vv[dn], pfA8, o[0][dn], 0, 0, 0); \
      o[1][dn] = __builtin_amdgcn_mfma_f32_16x16x32_f16(vv[dn], pfB8, o[1][dn], 0, 0, 0); \
    }                                                                          \
    o_l[0] = __builtin_amdgcn_mfma_f32_16x16x32_f16(ones8, pfA8, o_l[0], 0, 0, 0); \
    o_l[1] = __builtin_amdgcn_mfma_f32_16x16x32_f16(ones8, pfB8, o_l[1], 0, 0, 0); \
    __builtin_amdgcn_s_setprio(0);                                             \
    asm volatile("s_waitcnt vmcnt(0)" ::: "memory");                           \
    __syncthreads();                                                           \
  }

  if (useMask) {
    for (int k0 = 0; k0 < SEQ; k0 += 64) {
      ATTN_ITER(0, k0, 1)
      ATTN_ITER(1, k0 + 32, 1)
    }
  } else {
    for (int k0 = 0; k0 < SEQ; k0 += 64) {
      ATTN_ITER(0, k0, 0)
      ATTN_ITER(1, k0 + 32, 0)
    }
  }

  // lsum arrives complete per lane from the ones-row PV (no cross-lane reduce)
  const float invA = 1.0f / o_l[0][0], invB = 1.0f / o_l[1][0];
#pragma unroll
  for (int dn = 0; dn < 4; ++dn) {
    f16x4 wA, wB;
#pragma unroll
    for (int r = 0; r < 4; ++r) {
      wA[r] = (f16)(o[0][dn][r] * invA);
      wB[r] = (f16)(o[1][dn][r] * invB);
    }
    *(f16x4*)&ctx[(size_t)(b * SEQ + qw + lr) * INNER + h * 64 + dn * 16 + 4 * g] = wA;
    *(f16x4*)&ctx[(size_t)(b * SEQ + qw + 16 + lr) * INNER + h * 64 + dn * 16 + 4 * g] = wB;
  }
}

// ----------------------------------------------------------------- launch
extern "C" void kernel_launch(void* const* d_in, const int* in_sizes, int n_in,
                              void* d_out, int out_size, void* d_ws, size_t ws_size,
                              hipStream_t stream) {
  const float* hs   = (const float*)d_in[0];
  const float* mask = (const float*)d_in[2];
  const float* wq   = (const float*)d_in[3];
  const float* wk   = (const float*)d_in[4];
  const float* wv   = (const float*)d_in[5];
  const float* wo   = (const float*)d_in[6];
  const float* relb = (const float*)d_in[7];

  char* ws = (char*)d_ws;
  const size_t SZ16 = (size_t)MTOT * INNER * 2;      // 16 MiB
  const size_t WSZ  = (size_t)INNER * D_MODEL * 2;   // 2 MiB
  f16* hs16 = (f16*)(ws);                            // reused as ctx16 after QKV
  f16* q16  = (f16*)(ws + SZ16);
  f16* k16  = (f16*)(ws + 2 * SZ16);
  f16* vt16 = (f16*)(ws + 3 * SZ16);                 // V transposed+interleaved
  f16* wq16 = (f16*)(ws + 4 * SZ16);
  f16* wk16 = (f16*)(ws + 4 * SZ16 + WSZ);
  f16* wv16 = (f16*)(ws + 4 * SZ16 + 2 * WSZ);
  f16* wo16 = (f16*)(ws + 4 * SZ16 + 3 * WSZ);
  float* biasG = (float*)(ws + 4 * SZ16 + 4 * WSZ);  // 16*4352*4 B

  // wq pre-scaled by log2(e): QK^T scores land in the log2 domain.
  k_cvt<<<(MTOT * INNER / 4 + 255) / 256, 256, 0, stream>>>(hs, hs16, MTOT * INNER / 4, 1.0f);
  k_cvtw<<<dim3(INNER * D_MODEL / 4 / 256, 4), 256, 0, stream>>>(
      wq, wk, wv, wo, wq16, wk16, wv16, wo16);

  k_bias<<<dim3(BSTRIDE / 256, N_HEADS), 256, 0, stream>>>(relb, biasG);

  k_gemm_qkv<<<dim3(1536), 256, 0, stream>>>(
      hs16, wq16, wk16, wv16, q16, k16, vt16);

  k_attn<<<dim3(512), 512, 0, stream>>>(
      q16, k16, vt16, biasG, mask, hs16);

  k_gemm_out<<<dim3(512), 256, 0, stream>>>(
      hs16, wo16, (float*)d_out);
}

// Round 20
// 218.793 us; speedup vs baseline: 1.1015x; 1.1015x over previous
//
#include <hip/hip_runtime.h>
#include <cstdint>
#include <cstddef>

#define D_MODEL 1024
#define N_HEADS 16
#define INNER   1024
#define NBATCH  4
#define SEQ     2048
#define MTOT    (NBATCH * SEQ)   // 8192
#define LOG2E   1.44269504088896f
#define BSTRIDE 4352             // biasG per-head stride
#define MASKC   1442.695041f

typedef _Float16 f16;
typedef __attribute__((ext_vector_type(8))) _Float16 f16x8;
typedef __attribute__((ext_vector_type(4))) _Float16 f16x4;
typedef __attribute__((ext_vector_type(2))) _Float16 f16x2;
typedef __attribute__((ext_vector_type(2))) __fp16   h16x2;
typedef __attribute__((ext_vector_type(4))) float    f32x4;

// packed f32->f16 convert (RTZ) and dot2-accumulate shims
__device__ __forceinline__ f16x2 cvtpk(float x, float y) {
#if __has_builtin(__builtin_amdgcn_cvt_pkrtz)
  h16x2 r = __builtin_amdgcn_cvt_pkrtz(x, y);
  return __builtin_bit_cast(f16x2, r);
#else
  f16x2 r; r[0] = (f16)x; r[1] = (f16)y; return r;
#endif
}
__device__ __forceinline__ float dot2acc(f16x2 p, float acc) {
#if __has_builtin(__builtin_amdgcn_fdot2)
  h16x2 a = __builtin_bit_cast(h16x2, p);
  h16x2 one; one[0] = (__fp16)1.0f; one[1] = (__fp16)1.0f;
  return __builtin_amdgcn_fdot2(a, one, acc, false);
#else
  return acc + (float)p[0] + (float)p[1];
#endif
}

// ---------------------------------------------------------------- f32 -> f16
__global__ void k_cvt(const float* __restrict__ src, f16* __restrict__ dst, int n4, float scale) {
  int i = blockIdx.x * 256 + threadIdx.x;
  if (i < n4) {
    const float4 v = reinterpret_cast<const float4*>(src)[i];
    f16x4 h;
    h[0] = (f16)(v.x * scale); h[1] = (f16)(v.y * scale);
    h[2] = (f16)(v.z * scale); h[3] = (f16)(v.w * scale);
    reinterpret_cast<f16x4*>(dst)[i] = h;
  }
}

// fused weight converts: blockIdx.y selects {wq(scaled), wk, wv, wo}
__global__ void k_cvtw(const float* __restrict__ wq, const float* __restrict__ wk,
                       const float* __restrict__ wv, const float* __restrict__ wo,
                       f16* __restrict__ dq, f16* __restrict__ dk,
                       f16* __restrict__ dv, f16* __restrict__ dwo) {
  const int y = blockIdx.y;
  const float* src = y == 0 ? wq : (y == 1 ? wk : (y == 2 ? wv : wo));
  f16* dst = y == 0 ? dq : (y == 1 ? dk : (y == 2 ? dv : dwo));
  const float scale = y == 0 ? LOG2E : 1.0f;
  const int i = blockIdx.x * 256 + threadIdx.x;
  const float4 v = reinterpret_cast<const float4*>(src)[i];
  f16x4 h;
  h[0] = (f16)(v.x * scale); h[1] = (f16)(v.y * scale);
  h[2] = (f16)(v.z * scale); h[3] = (f16)(v.w * scale);
  reinterpret_cast<f16x4*>(dst)[i] = h;
}

// ------------------------------------------------- T5 relative bias, 1-D delta table
__global__ void k_bias(const float* __restrict__ relb, float* __restrict__ biasG) {
  const int i = blockIdx.x * 256 + threadIdx.x;  // 0..4351
  const int h = blockIdx.y;
  const int d = i - 2048;
  const int sgn = d > 0 ? 16 : 0;
  const int a = d < 0 ? -d : d;
  int bucket;
  if (a < 8) {
    bucket = a;
  } else {
    float t = logf((float)a / 8.0f);
    t = t / 2.772588722239781f;   // ln(16)
    t = t * 8.0f;
    int lg = 8 + (int)t;
    bucket = lg < 15 ? lg : 15;
  }
  biasG[h * BSTRIDE + i] = relb[(sgn + bucket) * N_HEADS + h] * LOG2E - MASKC;
}

// ------------------------------------------------- async global->LDS (16B)
__device__ __forceinline__ void gload_lds16(const void* g, void* l) {
  __builtin_amdgcn_global_load_lds(
      (const __attribute__((address_space(1))) unsigned int*)g,
      (__attribute__((address_space(3))) unsigned int*)l,
      16, 0, 0);
}

// ------------------------------------------------- C = A * W^T  (f16 in, K=1024)
// MODE 0: f16 row-major; MODE 1: f32 row-major; MODE 2: Vt interleaved.
template <int MODE>
__device__ __forceinline__ void gemm_body(const f16* __restrict__ A,
                                          const f16* __restrict__ W,
                                          void* __restrict__ Cp,
                                          int m0, int n0) {
  __shared__ __align__(16) f16 As[128 * 64];
  __shared__ __align__(16) f16 Bs[128 * 64];
  const int t = threadIdx.x;
  const int lane = t & 63;
  const int wid = t >> 6;
  const int wr = wid >> 1;
  const int wc = wid & 1;
  const int g = lane >> 4;
  const int lr = lane & 15;

  f32x4 acc[4][4] = {};
  const char* Ab = (const char*)A;
  const char* Wb = (const char*)W;

  for (int kt = 0; kt < D_MODEL / 64; ++kt) {
    const int k0 = kt * 64;
    __syncthreads();
#pragma unroll
    for (int i = 0; i < 4; ++i) {
      const int idx = i * 256 + t;
      const int row = idx >> 3;
      const int cb  = (idx & 7) * 16;
      gload_lds16(Ab + ((size_t)(m0 + row) * D_MODEL + k0) * 2 + cb, (char*)As + idx * 16);
      gload_lds16(Wb + ((size_t)(n0 + row) * D_MODEL + k0) * 2 + cb, (char*)Bs + idx * 16);
    }
    asm volatile("s_waitcnt vmcnt(0)" ::: "memory");
    __syncthreads();

    f16x8 af[4][2], bf[4][2];
#pragma unroll
    for (int mi = 0; mi < 4; ++mi)
#pragma unroll
      for (int kk = 0; kk < 2; ++kk)
        af[mi][kk] = *(const f16x8*)&As[(wr * 64 + mi * 16 + lr) * 64 + kk * 32 + g * 8];
#pragma unroll
    for (int ni = 0; ni < 4; ++ni)
#pragma unroll
      for (int kk = 0; kk < 2; ++kk)
        bf[ni][kk] = *(const f16x8*)&Bs[(wc * 64 + ni * 16 + lr) * 64 + kk * 32 + g * 8];
#pragma unroll
    for (int kk = 0; kk < 2; ++kk)
#pragma unroll
      for (int mi = 0; mi < 4; ++mi)
#pragma unroll
        for (int ni = 0; ni < 4; ++ni)
          acc[mi][ni] = __builtin_amdgcn_mfma_f32_16x16x32_f16(af[mi][kk], bf[ni][kk], acc[mi][ni], 0, 0, 0);
  }

#pragma unroll
  for (int mi = 0; mi < 4; ++mi)
#pragma unroll
    for (int ni = 0; ni < 4; ++ni) {
      const int n = n0 + wc * 64 + ni * 16 + lr;
      if (MODE == 2) {
        const int mbase = m0 + wr * 64 + mi * 16 + g * 4;   // s2, multiple of 4
        const int b2 = mbase >> 11, s2 = mbase & (SEQ - 1);
        const int h2 = n >> 6, d2 = n & 63;
        const int sub = ((s2 & 15) >> 2) * 8 + ((s2 >> 4) & 1) * 4;
        f16x4 w;
#pragma unroll
        for (int r = 0; r < 4; ++r) w[r] = (f16)acc[mi][ni][r];
        *(f16x4*)((f16*)Cp + ((size_t)((b2 * 16 + h2) * 64 + d2) * SEQ + (s2 >> 5) * 32 + sub)) = w;
      } else {
#pragma unroll
        for (int r = 0; r < 4; ++r) {
          const int m = m0 + wr * 64 + mi * 16 + g * 4 + r;
          if (MODE == 1)
            ((float*)Cp)[(size_t)m * INNER + n] = acc[mi][ni][r];
          else
            ((f16*)Cp)[(size_t)m * INNER + n] = (f16)acc[mi][ni][r];
        }
      }
    }
}

// 1D grid 1536, XCD-swizzled: all 8 n-tiles of one (z,y) A-panel on one XCD.
__global__ __launch_bounds__(256) void k_gemm_qkv(
    const f16* __restrict__ A,
    const f16* __restrict__ Wq, const f16* __restrict__ Wk, const f16* __restrict__ Wv,
    f16* __restrict__ Cq, f16* __restrict__ Ck, f16* __restrict__ Vt) {
  const int bid = (int)blockIdx.x;
  const int X = bid & 7, l = bid >> 3;     // X = xcd, l = 0..191
  const int zy = X * 24 + (l >> 3);        // 0..191
  const int x = l & 7;
  const int z = zy >> 6, y = zy & 63;
  if (z == 0)      gemm_body<0>(A, Wq, Cq, y * 128, x * 128);
  else if (z == 1) gemm_body<0>(A, Wk, Ck, y * 128, x * 128);
  else             gemm_body<2>(A, Wv, Vt, y * 128, x * 128);
}

// 1D grid 512, XCD-swizzled similarly.
__global__ __launch_bounds__(256) void k_gemm_out(
    const f16* __restrict__ A, const f16* __restrict__ W, float* __restrict__ C) {
  const int bid = (int)blockIdx.x;
  const int X = bid & 7, l = bid >> 3;     // l 0..63
  const int y = X * 8 + (l >> 3), x = l & 7;
  gemm_body<1>(A, W, C, y * 128, x * 128);
}

// ------------------------------------------------- flash attention
// ROUND-16 VERBATIM (best measured: 107.6us attn / 218.5us total).
// Block = 8 waves (512 thr) x 32 q = 256 q-rows, one (b,h).  KVBLK=32,
// 2-phase LDS double-buffer.  Quad-parity bias table (3x ds_read_b128/iter).
// launch_bounds(512,4) pins VGPR=64 -> 2 blocks/CU co-resident (occupancy
// 36%); at VGPR 72-84 the blocks serialize (occupancy 21%, +20us) -- the
// ~4MB spill this bound costs is cheaper than lost co-residency (r16 vs r19).
__global__ __launch_bounds__(512, 4) void k_attn(
    const f16* __restrict__ Q, const f16* __restrict__ K, const f16* __restrict__ Vt,
    const float* __restrict__ biasG, const float* __restrict__ mask,
    f16* __restrict__ ctx) {
  __shared__ __align__(16) float biasQ[4 * 2308]; // 4 parity copies, 36928 B
  __shared__ __align__(16) f16 Ks[2 * 2048];      // [k][d] swz bits 4-6, 4KB/buf
  __shared__ __align__(16) f16 Vs[2 * 2048];      // [d][32k interleaved] swz 4-5
  __shared__ int mflag;

  // XCD-aware remap: all 8 q-chunks of one (b,h) on one XCD; 8 bh per XCD.
  const int nb = (int)blockIdx.x;
  const int v = (nb & 7) * 64 + (nb >> 3);
  const int bh = v >> 3, qc = v & 7;
  const int b = bh >> 4, h = bh & 15;

  const int t = threadIdx.x, lane = t & 63, wid = t >> 6;  // wid 0..7
  const int g = lane >> 4, lr = lane & 15;
  const int qb = qc * 256;

  const float* maskB = mask + (size_t)b * SEQ;
  {
    // window w[j] = biasG[h][2048 + (j - (qb+255))]; copy c slot m = w[4m+c ..+3]
    const float* bgh = biasG + (size_t)h * BSTRIDE + (1793 - qb);
    for (int idx = t; idx < 4 * 576; idx += 512) {
      const int c = idx / 576, m = idx - c * 576;
      const int src = 4 * m + c;
      float4 w;
      w.x = bgh[src]; w.y = bgh[src + 1]; w.z = bgh[src + 2]; w.w = bgh[src + 3];
      *(float4*)&biasQ[c * 2308 + 4 * m] = w;
    }
  }
  if (t == 0) mflag = 1;
  __syncthreads();
  {
    bool bad = false;
    for (int i = t; i < SEQ; i += 512) bad |= (maskB[i] != 1.0f);
    if (bad) mflag = 0;
  }

  const char* Kg = (const char*)K + ((size_t)(b * SEQ) * INNER + h * 64) * 2;
  const char* Vg = (const char*)Vt + ((size_t)bh * 64) * SEQ * 2;

  // staging roles (wave-uniform split): t<256 -> K chunk, t>=256 -> V chunk
  const bool isK = t < 256;
  const int ts = t & 255;
  const int krow = ts >> 3, kch = ts & 7;
  const int vrow = ts >> 2, vch = ts & 3;
  const int stsrc = isK ? ((kch * 16) ^ ((krow & 7) << 4))
                        : ((vch * 16) ^ ((vrow & 3) << 4));

  const int qw = qb + wid * 32;

  f16x8 qa[2][2];
#pragma unroll
  for (int hh = 0; hh < 2; ++hh)
#pragma unroll
    for (int kk = 0; kk < 2; ++kk)
      qa[hh][kk] = *(const f16x8*)&Q[(size_t)(b * SEQ + qw + hh * 16 + lr) * INNER + h * 64 + kk * 32 + g * 8];

  // hoisted per-lane LDS byte offsets (loop-invariant)
  int koffs[2][2], voffs[4];
#pragma unroll
  for (int s = 0; s < 2; ++s)
#pragma unroll
    for (int hf = 0; hf < 2; ++hf)
      koffs[s][hf] = (s * 16 + lr) * 128 + ((hf * 64 + g * 16) ^ ((lr & 7) << 4));
#pragma unroll
  for (int dn = 0; dn < 4; ++dn)
    voffs[dn] = (dn * 16 + lr) * 64 + ((g * 16) ^ ((lr & 3) << 4));

  f32x4 o[2][4] = {};
  float mrun[2] = {-__builtin_inff(), -__builtin_inff()};
  float lsum[2] = {0.0f, 0.0f};

  // quad-parity bias base: j0(K0) = K0 + jb2; quads at j0, j0+16, j0+32.
  const int jbase = 255 + 4 * g - wid * 32 - lr;
  const int jb2 = jbase - 16;
  const char* bqPtr = (const char*)biasQ
                      + (size_t)((jb2 & 3) * 2308 + ((jb2 >> 2) << 2)) * 4;

  // prologue: stage tile 0 into buf 0 (one 16B chunk per thread)
  if (isK)
    gload_lds16(Kg + ((size_t)krow * INNER) * 2 + stsrc, (char*)Ks + ts * 16);
  else
    gload_lds16(Vg + ((size_t)vrow * SEQ) * 2 + stsrc,   (char*)Vs + ts * 16);
  asm volatile("s_waitcnt vmcnt(0)" ::: "memory");
  __syncthreads();
  const bool useMask = (mflag == 0);

#define ATTN_ITER(BUF, K0, MK)                                                 \
  {                                                                            \
    float4 mk0 = {}, mk1 = {};                                                 \
    if (MK) {                                                                  \
      mk0 = *(const float4*)(maskB + (K0) + 4 * g);                            \
      mk1 = *(const float4*)(maskB + (K0) + 16 + 4 * g);                       \
    }                                                                          \
    const int k0n_ = ((K0) + 32 < SEQ) ? (K0) + 32 : 0;                        \
    if (isK)                                                                   \
      gload_lds16(Kg + ((size_t)(k0n_ + krow) * INNER) * 2 + stsrc,            \
                  (char*)Ks + ((BUF) ^ 1) * 4096 + ts * 16);                   \
    else                                                                       \
      gload_lds16(Vg + ((size_t)vrow * SEQ + k0n_) * 2 + stsrc,                \
                  (char*)Vs + ((BUF) ^ 1) * 4096 + ts * 16);                   \
    const f32x4 bq0 = *(const f32x4*)(bqPtr + (K0) * 4);                       \
    const f32x4 bq1 = *(const f32x4*)(bqPtr + (K0) * 4 + 64);                  \
    const f32x4 bq2 = *(const f32x4*)(bqPtr + (K0) * 4 + 128);                 \
    f16x8 kf[2][2];                                                            \
    _Pragma("unroll") for (int s = 0; s < 2; ++s)                              \
      _Pragma("unroll") for (int hf = 0; hf < 2; ++hf)                         \
        kf[s][hf] = *(const f16x8*)((const char*)Ks + (BUF) * 4096 + koffs[s][hf]); \
    f16x8 vv[4];                                                               \
    _Pragma("unroll") for (int dn = 0; dn < 4; ++dn)                           \
      vv[dn] = *(const f16x8*)((const char*)Vs + (BUF) * 4096 + voffs[dn]);    \
    f32x4 sg[2][2];                                                            \
    __builtin_amdgcn_s_setprio(1);                                             \
    _Pragma("unroll") for (int hh = 0; hh < 2; ++hh)                           \
      _Pragma("unroll") for (int s = 0; s < 2; ++s) {                          \
        const f32x4 bq = hh ? (s ? bq1 : bq0) : (s ? bq2 : bq1);               \
        f32x4 z;                                                               \
        if (MK) {                                                              \
          const float* mkp = (s == 0) ? (const float*)&mk0 : (const float*)&mk1; \
          _Pragma("unroll") for (int r = 0; r < 4; ++r)                        \
            z[r] = fmaf(mkp[r], MASKC, bq[r]);                                 \
        } else {                                                               \
          z = bq;                                                              \
        }                                                                      \
        z = __builtin_amdgcn_mfma_f32_16x16x32_f16(kf[s][0], qa[hh][0], z, 0, 0, 0); \
        z = __builtin_amdgcn_mfma_f32_16x16x32_f16(kf[s][1], qa[hh][1], z, 0, 0, 0); \
        sg[hh][s] = z;                                                         \
      }                                                                        \
    __builtin_amdgcn_s_setprio(0);                                             \
    float mxA = fmaxf(fmaxf(fmaxf(sg[0][0][0], sg[0][0][1]), fmaxf(sg[0][0][2], sg[0][0][3])), \
                      fmaxf(fmaxf(sg[0][1][0], sg[0][1][1]), fmaxf(sg[0][1][2], sg[0][1][3]))); \
    float mxB = fmaxf(fmaxf(fmaxf(sg[1][0][0], sg[1][0][1]), fmaxf(sg[1][0][2], sg[1][0][3])), \
                      fmaxf(fmaxf(sg[1][1][0], sg[1][1][1]), fmaxf(sg[1][1][2], sg[1][1][3]))); \
    if (__any((mxA > mrun[0] + 11.5415603f) || (mxB > mrun[1] + 11.5415603f))) { \
      mxA = fmaxf(mxA, __shfl_xor(mxA, 16));                                   \
      mxB = fmaxf(mxB, __shfl_xor(mxB, 16));                                   \
      mxA = fmaxf(mxA, __shfl_xor(mxA, 32));                                   \
      mxB = fmaxf(mxB, __shfl_xor(mxB, 32));                                   \
      const float mnA = fmaxf(mrun[0], mxA), mnB = fmaxf(mrun[1], mxB);        \
      const float aA = __builtin_amdgcn_exp2f(mrun[0] - mnA);                  \
      const float aB = __builtin_amdgcn_exp2f(mrun[1] - mnB);                  \
      lsum[0] *= aA; lsum[1] *= aB;                                            \
      _Pragma("unroll") for (int dn = 0; dn < 4; ++dn)                         \
        _Pragma("unroll") for (int r = 0; r < 4; ++r) {                        \
          o[0][dn][r] *= aA; o[1][dn][r] *= aB;                                \
        }                                                                      \
      mrun[0] = mnA; mrun[1] = mnB;                                            \
    }                                                                          \
    f16x8 pfA8, pfB8;                                                          \
    _Pragma("unroll") for (int s = 0; s < 2; ++s) {                            \
      float eA[4], eB[4];                                                      \
      _Pragma("unroll") for (int r = 0; r < 4; ++r) {                          \
        eA[r] = __builtin_amdgcn_exp2f(sg[0][s][r] - mrun[0]);                 \
        eB[r] = __builtin_amdgcn_exp2f(sg[1][s][r] - mrun[1]);                 \
      }                                                                        \
      const f16x2 a0 = cvtpk(eA[0], eA[1]), a1 = cvtpk(eA[2], eA[3]);          \
      const f16x2 b0 = cvtpk(eB[0], eB[1]), b1 = cvtpk(eB[2], eB[3]);          \
      lsum[0] = dot2acc(a0, lsum[0]); lsum[0] = dot2acc(a1, lsum[0]);          \
      lsum[1] = dot2acc(b0, lsum[1]); lsum[1] = dot2acc(b1, lsum[1]);          \
      pfA8[s * 4 + 0] = a0[0]; pfA8[s * 4 + 1] = a0[1];                        \
      pfA8[s * 4 + 2] = a1[0]; pfA8[s * 4 + 3] = a1[1];                        \
      pfB8[s * 4 + 0] = b0[0]; pfB8[s * 4 + 1] = b0[1];                        \
      pfB8[s * 4 + 2] = b1[0]; pfB8[s * 4 + 3] = b1[1];                        \
    }                                                                          \
    __builtin_amdgcn_s_setprio(1);                                             \
    _Pragma("unroll") for (int dn = 0; dn < 4; ++dn) {                         \
      o[0][dn] = __builtin_amdgcn_mfma_f32_16x16x32_f16(vv[dn], pfA8, o[0][dn], 0, 0, 0); \
      o[1][dn] = __builtin_amdgcn_mfma_f32_16x16x32_f16(vv[dn], pfB8, o[1][dn], 0, 0, 0); \
    }                                                                          \
    __builtin_amdgcn_s_setprio(0);                                             \
    asm volatile("s_waitcnt vmcnt(0)" ::: "memory");                           \
    __syncthreads();                                                           \
  }

  if (useMask) {
    for (int k0 = 0; k0 < SEQ; k0 += 64) {
      ATTN_ITER(0, k0, 1)
      ATTN_ITER(1, k0 + 32, 1)
    }
  } else {
    for (int k0 = 0; k0 < SEQ; k0 += 64) {
      ATTN_ITER(0, k0, 0)
      ATTN_ITER(1, k0 + 32, 0)
    }
  }

  // epilogue: reduce per-lane partial sums across the 4 g-groups of each row
  lsum[0] += __shfl_xor(lsum[0], 16);
  lsum[1] += __shfl_xor(lsum[1], 16);
  lsum[0] += __shfl_xor(lsum[0], 32);
  lsum[1] += __shfl_xor(lsum[1], 32);

  const float invA = 1.0f / lsum[0], invB = 1.0f / lsum[1];
#pragma unroll
  for (int dn = 0; dn < 4; ++dn) {
    f16x4 wA, wB;
#pragma unroll
    for (int r = 0; r < 4; ++r) {
      wA[r] = (f16)(o[0][dn][r] * invA);
      wB[r] = (f16)(o[1][dn][r] * invB);
    }
    *(f16x4*)&ctx[(size_t)(b * SEQ + qw + lr) * INNER + h * 64 + dn * 16 + 4 * g] = wA;
    *(f16x4*)&ctx[(size_t)(b * SEQ + qw + 16 + lr) * INNER + h * 64 + dn * 16 + 4 * g] = wB;
  }
}

// ----------------------------------------------------------------- launch
extern "C" void kernel_launch(void* const* d_in, const int* in_sizes, int n_in,
                              void* d_out, int out_size, void* d_ws, size_t ws_size,
                              hipStream_t stream) {
  const float* hs   = (const float*)d_in[0];
  const float* mask = (const float*)d_in[2];
  const float* wq   = (const float*)d_in[3];
  const float* wk   = (const float*)d_in[4];
  const float* wv   = (const float*)d_in[5];
  const float* wo   = (const float*)d_in[6];
  const float* relb = (const float*)d_in[7];

  char* ws = (char*)d_ws;
  const size_t SZ16 = (size_t)MTOT * INNER * 2;      // 16 MiB
  const size_t WSZ  = (size_t)INNER * D_MODEL * 2;   // 2 MiB
  f16* hs16 = (f16*)(ws);                            // reused as ctx16 after QKV
  f16* q16  = (f16*)(ws + SZ16);
  f16* k16  = (f16*)(ws + 2 * SZ16);
  f16* vt16 = (f16*)(ws + 3 * SZ16);                 // V transposed+interleaved
  f16* wq16 = (f16*)(ws + 4 * SZ16);
  f16* wk16 = (f16*)(ws + 4 * SZ16 + WSZ);
  f16* wv16 = (f16*)(ws + 4 * SZ16 + 2 * WSZ);
  f16* wo16 = (f16*)(ws + 4 * SZ16 + 3 * WSZ);
  float* biasG = (float*)(ws + 4 * SZ16 + 4 * WSZ);  // 16*4352*4 B

  // wq pre-scaled by log2(e): QK^T scores land in the log2 domain.
  k_cvt<<<(MTOT * INNER / 4 + 255) / 256, 256, 0, stream>>>(hs, hs16, MTOT * INNER / 4, 1.0f);
  k_cvtw<<<dim3(INNER * D_MODEL / 4 / 256, 4), 256, 0, stream>>>(
      wq, wk, wv, wo, wq16, wk16, wv16, wo16);

  k_bias<<<dim3(BSTRIDE / 256, N_HEADS), 256, 0, stream>>>(relb, biasG);

  k_gemm_qkv<<<dim3(1536), 256, 0, stream>>>(
      hs16, wq16, wk16, wv16, q16, k16, vt16);

  k_attn<<<dim3(512), 512, 0, stream>>>(
      q16, k16, vt16, biasG, mask, hs16);

  k_gemm_out<<<dim3(512), 256, 0, stream>>>(
      hs16, wo16, (float*)d_out);
}

// Round 21
// 217.993 us; speedup vs baseline: 1.1056x; 1.0037x over previous
//
#include <hip/hip_runtime.h>
#include <cstdint>
#include <cstddef>

#define D_MODEL 1024
#define N_HEADS 16
#define INNER   1024
#define NBATCH  4
#define SEQ     2048
#define MTOT    (NBATCH * SEQ)   // 8192
#define LOG2E   1.44269504088896f
#define BSTRIDE 4352             // biasG per-head stride
#define MASKC   1442.695041f

typedef _Float16 f16;
typedef __attribute__((ext_vector_type(8))) _Float16 f16x8;
typedef __attribute__((ext_vector_type(4))) _Float16 f16x4;
typedef __attribute__((ext_vector_type(2))) _Float16 f16x2;
typedef __attribute__((ext_vector_type(2))) __fp16   h16x2;
typedef __attribute__((ext_vector_type(4))) float    f32x4;

// packed f32->f16 convert (RTZ) and dot2-accumulate shims
__device__ __forceinline__ f16x2 cvtpk(float x, float y) {
#if __has_builtin(__builtin_amdgcn_cvt_pkrtz)
  h16x2 r = __builtin_amdgcn_cvt_pkrtz(x, y);
  return __builtin_bit_cast(f16x2, r);
#else
  f16x2 r; r[0] = (f16)x; r[1] = (f16)y; return r;
#endif
}
__device__ __forceinline__ float dot2acc(f16x2 p, float acc) {
#if __has_builtin(__builtin_amdgcn_fdot2)
  h16x2 a = __builtin_bit_cast(h16x2, p);
  h16x2 one; one[0] = (__fp16)1.0f; one[1] = (__fp16)1.0f;
  return __builtin_amdgcn_fdot2(a, one, acc, false);
#else
  return acc + (float)p[0] + (float)p[1];
#endif
}

// ---------------------------------------------------------------- f32 -> f16
__global__ void k_cvt(const float* __restrict__ src, f16* __restrict__ dst, int n4, float scale) {
  int i = blockIdx.x * 256 + threadIdx.x;
  if (i < n4) {
    const float4 v = reinterpret_cast<const float4*>(src)[i];
    f16x4 h;
    h[0] = (f16)(v.x * scale); h[1] = (f16)(v.y * scale);
    h[2] = (f16)(v.z * scale); h[3] = (f16)(v.w * scale);
    reinterpret_cast<f16x4*>(dst)[i] = h;
  }
}

// fused weight converts: blockIdx.y selects {wq(scaled), wk, wv, wo}
__global__ void k_cvtw(const float* __restrict__ wq, const float* __restrict__ wk,
                       const float* __restrict__ wv, const float* __restrict__ wo,
                       f16* __restrict__ dq, f16* __restrict__ dk,
                       f16* __restrict__ dv, f16* __restrict__ dwo) {
  const int y = blockIdx.y;
  const float* src = y == 0 ? wq : (y == 1 ? wk : (y == 2 ? wv : wo));
  f16* dst = y == 0 ? dq : (y == 1 ? dk : (y == 2 ? dv : dwo));
  const float scale = y == 0 ? LOG2E : 1.0f;
  const int i = blockIdx.x * 256 + threadIdx.x;
  const float4 v = reinterpret_cast<const float4*>(src)[i];
  f16x4 h;
  h[0] = (f16)(v.x * scale); h[1] = (f16)(v.y * scale);
  h[2] = (f16)(v.z * scale); h[3] = (f16)(v.w * scale);
  reinterpret_cast<f16x4*>(dst)[i] = h;
}

// ------------------------------------------------- T5 relative bias, 1-D delta table
__global__ void k_bias(const float* __restrict__ relb, float* __restrict__ biasG) {
  const int i = blockIdx.x * 256 + threadIdx.x;  // 0..4351
  const int h = blockIdx.y;
  const int d = i - 2048;
  const int sgn = d > 0 ? 16 : 0;
  const int a = d < 0 ? -d : d;
  int bucket;
  if (a < 8) {
    bucket = a;
  } else {
    float t = logf((float)a / 8.0f);
    t = t / 2.772588722239781f;   // ln(16)
    t = t * 8.0f;
    int lg = 8 + (int)t;
    bucket = lg < 15 ? lg : 15;
  }
  biasG[h * BSTRIDE + i] = relb[(sgn + bucket) * N_HEADS + h] * LOG2E - MASKC;
}

// ------------------------------------------------- async global->LDS (16B)
__device__ __forceinline__ void gload_lds16(const void* g, void* l) {
  __builtin_amdgcn_global_load_lds(
      (const __attribute__((address_space(1))) unsigned int*)g,
      (__attribute__((address_space(3))) unsigned int*)l,
      16, 0, 0);
}

// ------------------------------------------------- C = A * W^T  (f16 in, K=1024)
// MODE 0: f16 row-major; MODE 1: f32 row-major; MODE 2: Vt interleaved.
template <int MODE>
__device__ __forceinline__ void gemm_body(const f16* __restrict__ A,
                                          const f16* __restrict__ W,
                                          void* __restrict__ Cp,
                                          int m0, int n0) {
  __shared__ __align__(16) f16 As[128 * 64];
  __shared__ __align__(16) f16 Bs[128 * 64];
  const int t = threadIdx.x;
  const int lane = t & 63;
  const int wid = t >> 6;
  const int wr = wid >> 1;
  const int wc = wid & 1;
  const int g = lane >> 4;
  const int lr = lane & 15;

  f32x4 acc[4][4] = {};
  const char* Ab = (const char*)A;
  const char* Wb = (const char*)W;

  for (int kt = 0; kt < D_MODEL / 64; ++kt) {
    const int k0 = kt * 64;
    __syncthreads();
#pragma unroll
    for (int i = 0; i < 4; ++i) {
      const int idx = i * 256 + t;
      const int row = idx >> 3;
      const int cb  = (idx & 7) * 16;
      gload_lds16(Ab + ((size_t)(m0 + row) * D_MODEL + k0) * 2 + cb, (char*)As + idx * 16);
      gload_lds16(Wb + ((size_t)(n0 + row) * D_MODEL + k0) * 2 + cb, (char*)Bs + idx * 16);
    }
    asm volatile("s_waitcnt vmcnt(0)" ::: "memory");
    __syncthreads();

    f16x8 af[4][2], bf[4][2];
#pragma unroll
    for (int mi = 0; mi < 4; ++mi)
#pragma unroll
      for (int kk = 0; kk < 2; ++kk)
        af[mi][kk] = *(const f16x8*)&As[(wr * 64 + mi * 16 + lr) * 64 + kk * 32 + g * 8];
#pragma unroll
    for (int ni = 0; ni < 4; ++ni)
#pragma unroll
      for (int kk = 0; kk < 2; ++kk)
        bf[ni][kk] = *(const f16x8*)&Bs[(wc * 64 + ni * 16 + lr) * 64 + kk * 32 + g * 8];
#pragma unroll
    for (int kk = 0; kk < 2; ++kk)
#pragma unroll
      for (int mi = 0; mi < 4; ++mi)
#pragma unroll
        for (int ni = 0; ni < 4; ++ni)
          acc[mi][ni] = __builtin_amdgcn_mfma_f32_16x16x32_f16(af[mi][kk], bf[ni][kk], acc[mi][ni], 0, 0, 0);
  }

#pragma unroll
  for (int mi = 0; mi < 4; ++mi)
#pragma unroll
    for (int ni = 0; ni < 4; ++ni) {
      const int n = n0 + wc * 64 + ni * 16 + lr;
      if (MODE == 2) {
        const int mbase = m0 + wr * 64 + mi * 16 + g * 4;   // s2, multiple of 4
        const int b2 = mbase >> 11, s2 = mbase & (SEQ - 1);
        const int h2 = n >> 6, d2 = n & 63;
        const int sub = ((s2 & 15) >> 2) * 8 + ((s2 >> 4) & 1) * 4;
        f16x4 w;
#pragma unroll
        for (int r = 0; r < 4; ++r) w[r] = (f16)acc[mi][ni][r];
        *(f16x4*)((f16*)Cp + ((size_t)((b2 * 16 + h2) * 64 + d2) * SEQ + (s2 >> 5) * 32 + sub)) = w;
      } else {
#pragma unroll
        for (int r = 0; r < 4; ++r) {
          const int m = m0 + wr * 64 + mi * 16 + g * 4 + r;
          if (MODE == 1)
            ((float*)Cp)[(size_t)m * INNER + n] = acc[mi][ni][r];
          else
            ((f16*)Cp)[(size_t)m * INNER + n] = (f16)acc[mi][ni][r];
        }
      }
    }
}

// 1D grid 1536, XCD-swizzled: all 8 n-tiles of one (z,y) A-panel on one XCD.
__global__ __launch_bounds__(256) void k_gemm_qkv(
    const f16* __restrict__ A,
    const f16* __restrict__ Wq, const f16* __restrict__ Wk, const f16* __restrict__ Wv,
    f16* __restrict__ Cq, f16* __restrict__ Ck, f16* __restrict__ Vt) {
  const int bid = (int)blockIdx.x;
  const int X = bid & 7, l = bid >> 3;     // X = xcd, l = 0..191
  const int zy = X * 24 + (l >> 3);        // 0..191
  const int x = l & 7;
  const int z = zy >> 6, y = zy & 63;
  if (z == 0)      gemm_body<0>(A, Wq, Cq, y * 128, x * 128);
  else if (z == 1) gemm_body<0>(A, Wk, Ck, y * 128, x * 128);
  else             gemm_body<2>(A, Wv, Vt, y * 128, x * 128);
}

// 1D grid 512, XCD-swizzled similarly.
__global__ __launch_bounds__(256) void k_gemm_out(
    const f16* __restrict__ A, const f16* __restrict__ W, float* __restrict__ C) {
  const int bid = (int)blockIdx.x;
  const int X = bid & 7, l = bid >> 3;     // l 0..63
  const int y = X * 8 + (l >> 3), x = l & 7;
  gemm_body<1>(A, W, C, y * 128, x * 128);
}

// ------------------------------------------------- flash attention
// Round-16 structure + COUNTED VMCNT pipeline (T4): 4 LDS buffers, distance-2
// staging. Iter i computes buf[i%4], issues tile i+2 into buf[(i+2)%4], then
// waits vmcnt(1) — the just-issued load stays in flight ACROSS the barrier;
// only the previous tile (needed next iter) must have landed.  Per thread
// exactly 1 gload_lds/iter -> the count is deterministic; mask-path compiler
// waits only tighten it.  launch_bounds(512,4) pins VGPR=64 (2-block/CU
// co-residency; r16 vs r19 A/B).
__global__ __launch_bounds__(512, 4) void k_attn(
    const f16* __restrict__ Q, const f16* __restrict__ K, const f16* __restrict__ Vt,
    const float* __restrict__ biasG, const float* __restrict__ mask,
    f16* __restrict__ ctx) {
  __shared__ __align__(16) float biasQ[4 * 2308]; // 4 parity copies, 36928 B
  __shared__ __align__(16) f16 Ks[4 * 2048];      // 4 bufs x 4KB, swz bits 4-6
  __shared__ __align__(16) f16 Vs[4 * 2048];      // 4 bufs x 4KB, swz bits 4-5
  __shared__ int mflag;

  // XCD-aware remap: all 8 q-chunks of one (b,h) on one XCD; 8 bh per XCD.
  const int nb = (int)blockIdx.x;
  const int v = (nb & 7) * 64 + (nb >> 3);
  const int bh = v >> 3, qc = v & 7;
  const int b = bh >> 4, h = bh & 15;

  const int t = threadIdx.x, lane = t & 63, wid = t >> 6;  // wid 0..7
  const int g = lane >> 4, lr = lane & 15;
  const int qb = qc * 256;

  const float* maskB = mask + (size_t)b * SEQ;
  {
    // window w[j] = biasG[h][2048 + (j - (qb+255))]; copy c slot m = w[4m+c ..+3]
    const float* bgh = biasG + (size_t)h * BSTRIDE + (1793 - qb);
    for (int idx = t; idx < 4 * 576; idx += 512) {
      const int c = idx / 576, m = idx - c * 576;
      const int src = 4 * m + c;
      float4 w;
      w.x = bgh[src]; w.y = bgh[src + 1]; w.z = bgh[src + 2]; w.w = bgh[src + 3];
      *(float4*)&biasQ[c * 2308 + 4 * m] = w;
    }
  }
  if (t == 0) mflag = 1;
  __syncthreads();
  {
    bool bad = false;
    for (int i = t; i < SEQ; i += 512) bad |= (maskB[i] != 1.0f);
    if (bad) mflag = 0;
  }

  const char* Kg = (const char*)K + ((size_t)(b * SEQ) * INNER + h * 64) * 2;
  const char* Vg = (const char*)Vt + ((size_t)bh * 64) * SEQ * 2;

  // staging roles (wave-uniform split): t<256 -> K chunk, t>=256 -> V chunk
  const bool isK = t < 256;
  const int ts = t & 255;
  const int krow = ts >> 3, kch = ts & 7;
  const int vrow = ts >> 2, vch = ts & 3;
  const int stsrc = isK ? ((kch * 16) ^ ((krow & 7) << 4))
                        : ((vch * 16) ^ ((vrow & 3) << 4));

  const int qw = qb + wid * 32;

  f16x8 qa[2][2];
#pragma unroll
  for (int hh = 0; hh < 2; ++hh)
#pragma unroll
    for (int kk = 0; kk < 2; ++kk)
      qa[hh][kk] = *(const f16x8*)&Q[(size_t)(b * SEQ + qw + hh * 16 + lr) * INNER + h * 64 + kk * 32 + g * 8];

  // hoisted per-lane LDS byte offsets (loop-invariant)
  int koffs[2][2], voffs[4];
#pragma unroll
  for (int s = 0; s < 2; ++s)
#pragma unroll
    for (int hf = 0; hf < 2; ++hf)
      koffs[s][hf] = (s * 16 + lr) * 128 + ((hf * 64 + g * 16) ^ ((lr & 7) << 4));
#pragma unroll
  for (int dn = 0; dn < 4; ++dn)
    voffs[dn] = (dn * 16 + lr) * 64 + ((g * 16) ^ ((lr & 3) << 4));

  f32x4 o[2][4] = {};
  float mrun[2] = {-__builtin_inff(), -__builtin_inff()};
  float lsum[2] = {0.0f, 0.0f};

  // quad-parity bias base: j0(K0) = K0 + jb2; quads at j0, j0+16, j0+32.
  const int jbase = 255 + 4 * g - wid * 32 - lr;
  const int jb2 = jbase - 16;
  const char* bqPtr = (const char*)biasQ
                      + (size_t)((jb2 & 3) * 2308 + ((jb2 >> 2) << 2)) * 4;

  // staging helper: stage 32-key tile with key base KB into buffer WB
#define STAGE(WB, KB)                                                          \
  {                                                                            \
    if (isK)                                                                   \
      gload_lds16(Kg + ((size_t)((KB) + krow) * INNER) * 2 + stsrc,            \
                  (char*)Ks + (WB) * 4096 + ts * 16);                          \
    else                                                                       \
      gload_lds16(Vg + ((size_t)vrow * SEQ + (KB)) * 2 + stsrc,                \
                  (char*)Vs + (WB) * 4096 + ts * 16);                          \
  }

  // prologue: stage tiles 0 and 1; wait for tile 0 (1 load may stay in flight)
  STAGE(0, 0)
  STAGE(1, 32)
  asm volatile("s_waitcnt vmcnt(1)" ::: "memory");
  __syncthreads();
  const bool useMask = (mflag == 0);

#define ATTN_ITER(BUF, K0, MK)                                                 \
  {                                                                            \
    float4 mk0 = {}, mk1 = {};                                                 \
    if (MK) {                                                                  \
      mk0 = *(const float4*)(maskB + (K0) + 4 * g);                            \
      mk1 = *(const float4*)(maskB + (K0) + 16 + 4 * g);                       \
    }                                                                          \
    const int kst_ = ((K0) + 64 < SEQ) ? (K0) + 64 : 0;                        \
    STAGE(((BUF) + 2) & 3, kst_)                                               \
    const f32x4 bq0 = *(const f32x4*)(bqPtr + (K0) * 4);                       \
    const f32x4 bq1 = *(const f32x4*)(bqPtr + (K0) * 4 + 64);                  \
    const f32x4 bq2 = *(const f32x4*)(bqPtr + (K0) * 4 + 128);                 \
    f16x8 kf[2][2];                                                            \
    _Pragma("unroll") for (int s = 0; s < 2; ++s)                              \
      _Pragma("unroll") for (int hf = 0; hf < 2; ++hf)                         \
        kf[s][hf] = *(const f16x8*)((const char*)Ks + (BUF) * 4096 + koffs[s][hf]); \
    f16x8 vv[4];                                                               \
    _Pragma("unroll") for (int dn = 0; dn < 4; ++dn)                           \
      vv[dn] = *(const f16x8*)((const char*)Vs + (BUF) * 4096 + voffs[dn]);    \
    f32x4 sg[2][2];                                                            \
    __builtin_amdgcn_s_setprio(1);                                             \
    _Pragma("unroll") for (int hh = 0; hh < 2; ++hh)                           \
      _Pragma("unroll") for (int s = 0; s < 2; ++s) {                          \
        const f32x4 bq = hh ? (s ? bq1 : bq0) : (s ? bq2 : bq1);               \
        f32x4 z;                                                               \
        if (MK) {                                                              \
          const float* mkp = (s == 0) ? (const float*)&mk0 : (const float*)&mk1; \
          _Pragma("unroll") for (int r = 0; r < 4; ++r)                        \
            z[r] = fmaf(mkp[r], MASKC, bq[r]);                                 \
        } else {                                                               \
          z = bq;                                                              \
        }                                                                      \
        z = __builtin_amdgcn_mfma_f32_16x16x32_f16(kf[s][0], qa[hh][0], z, 0, 0, 0); \
        z = __builtin_amdgcn_mfma_f32_16x16x32_f16(kf[s][1], qa[hh][1], z, 0, 0, 0); \
        sg[hh][s] = z;                                                         \
      }                                                                        \
    __builtin_amdgcn_s_setprio(0);                                             \
    float mxA = fmaxf(fmaxf(fmaxf(sg[0][0][0], sg[0][0][1]), fmaxf(sg[0][0][2], sg[0][0][3])), \
                      fmaxf(fmaxf(sg[0][1][0], sg[0][1][1]), fmaxf(sg[0][1][2], sg[0][1][3]))); \
    float mxB = fmaxf(fmaxf(fmaxf(sg[1][0][0], sg[1][0][1]), fmaxf(sg[1][0][2], sg[1][0][3])), \
                      fmaxf(fmaxf(sg[1][1][0], sg[1][1][1]), fmaxf(sg[1][1][2], sg[1][1][3]))); \
    if (__any((mxA > mrun[0] + 11.5415603f) || (mxB > mrun[1] + 11.5415603f))) { \
      mxA = fmaxf(mxA, __shfl_xor(mxA, 16));                                   \
      mxB = fmaxf(mxB, __shfl_xor(mxB, 16));                                   \
      mxA = fmaxf(mxA, __shfl_xor(mxA, 32));                                   \
      mxB = fmaxf(mxB, __shfl_xor(mxB, 32));                                   \
      const float mnA = fmaxf(mrun[0], mxA), mnB = fmaxf(mrun[1], mxB);        \
      const float aA = __builtin_amdgcn_exp2f(mrun[0] - mnA);                  \
      const float aB = __builtin_amdgcn_exp2f(mrun[1] - mnB);                  \
      lsum[0] *= aA; lsum[1] *= aB;                                            \
      _Pragma("unroll") for (int dn = 0; dn < 4; ++dn)                         \
        _Pragma("unroll") for (int r = 0; r < 4; ++r) {                        \
          o[0][dn][r] *= aA; o[1][dn][r] *= aB;                                \
        }                                                                      \
      mrun[0] = mnA; mrun[1] = mnB;                                            \
    }                                                                          \
    f16x8 pfA8, pfB8;                                                          \
    _Pragma("unroll") for (int s = 0; s < 2; ++s) {                            \
      float eA[4], eB[4];                                                      \
      _Pragma("unroll") for (int r = 0; r < 4; ++r) {                          \
        eA[r] = __builtin_amdgcn_exp2f(sg[0][s][r] - mrun[0]);                 \
        eB[r] = __builtin_amdgcn_exp2f(sg[1][s][r] - mrun[1]);                 \
      }                                                                        \
      const f16x2 a0 = cvtpk(eA[0], eA[1]), a1 = cvtpk(eA[2], eA[3]);          \
      const f16x2 b0 = cvtpk(eB[0], eB[1]), b1 = cvtpk(eB[2], eB[3]);          \
      lsum[0] = dot2acc(a0, lsum[0]); lsum[0] = dot2acc(a1, lsum[0]);          \
      lsum[1] = dot2acc(b0, lsum[1]); lsum[1] = dot2acc(b1, lsum[1]);          \
      pfA8[s * 4 + 0] = a0[0]; pfA8[s * 4 + 1] = a0[1];                        \
      pfA8[s * 4 + 2] = a1[0]; pfA8[s * 4 + 3] = a1[1];                        \
      pfB8[s * 4 + 0] = b0[0]; pfB8[s * 4 + 1] = b0[1];                        \
      pfB8[s * 4 + 2] = b1[0]; pfB8[s * 4 + 3] = b1[1];                        \
    }                                                                          \
    __builtin_amdgcn_s_setprio(1);                                             \
    _Pragma("unroll") for (int dn = 0; dn < 4; ++dn) {                         \
      o[0][dn] = __builtin_amdgcn_mfma_f32_16x16x32_f16(vv[dn], pfA8, o[0][dn], 0, 0, 0); \
      o[1][dn] = __builtin_amdgcn_mfma_f32_16x16x32_f16(vv[dn], pfB8, o[1][dn], 0, 0, 0); \
    }                                                                          \
    __builtin_amdgcn_s_setprio(0);                                             \
    asm volatile("s_waitcnt vmcnt(1)" ::: "memory");                           \
    __syncthreads();                                                           \
  }

  if (useMask) {
    for (int k0 = 0; k0 < SEQ; k0 += 128) {
      ATTN_ITER(0, k0, 1)
      ATTN_ITER(1, k0 + 32, 1)
      ATTN_ITER(2, k0 + 64, 1)
      ATTN_ITER(3, k0 + 96, 1)
    }
  } else {
    for (int k0 = 0; k0 < SEQ; k0 += 128) {
      ATTN_ITER(0, k0, 0)
      ATTN_ITER(1, k0 + 32, 0)
      ATTN_ITER(2, k0 + 64, 0)
      ATTN_ITER(3, k0 + 96, 0)
    }
  }

  // epilogue: reduce per-lane partial sums across the 4 g-groups of each row
  lsum[0] += __shfl_xor(lsum[0], 16);
  lsum[1] += __shfl_xor(lsum[1], 16);
  lsum[0] += __shfl_xor(lsum[0], 32);
  lsum[1] += __shfl_xor(lsum[1], 32);

  const float invA = 1.0f / lsum[0], invB = 1.0f / lsum[1];
#pragma unroll
  for (int dn = 0; dn < 4; ++dn) {
    f16x4 wA, wB;
#pragma unroll
    for (int r = 0; r < 4; ++r) {
      wA[r] = (f16)(o[0][dn][r] * invA);
      wB[r] = (f16)(o[1][dn][r] * invB);
    }
    *(f16x4*)&ctx[(size_t)(b * SEQ + qw + lr) * INNER + h * 64 + dn * 16 + 4 * g] = wA;
    *(f16x4*)&ctx[(size_t)(b * SEQ + qw + 16 + lr) * INNER + h * 64 + dn * 16 + 4 * g] = wB;
  }
}

// ----------------------------------------------------------------- launch
extern "C" void kernel_launch(void* const* d_in, const int* in_sizes, int n_in,
                              void* d_out, int out_size, void* d_ws, size_t ws_size,
                              hipStream_t stream) {
  const float* hs   = (const float*)d_in[0];
  const float* mask = (const float*)d_in[2];
  const float* wq   = (const float*)d_in[3];
  const float* wk   = (const float*)d_in[4];
  const float* wv   = (const float*)d_in[5];
  const float* wo   = (const float*)d_in[6];
  const float* relb = (const float*)d_in[7];

  char* ws = (char*)d_ws;
  const size_t SZ16 = (size_t)MTOT * INNER * 2;      // 16 MiB
  const size_t WSZ  = (size_t)INNER * D_MODEL * 2;   // 2 MiB
  f16* hs16 = (f16*)(ws);                            // reused as ctx16 after QKV
  f16* q16  = (f16*)(ws + SZ16);
  f16* k16  = (f16*)(ws + 2 * SZ16);
  f16* vt16 = (f16*)(ws + 3 * SZ16);                 // V transposed+interleaved
  f16* wq16 = (f16*)(ws + 4 * SZ16);
  f16* wk16 = (f16*)(ws + 4 * SZ16 + WSZ);
  f16* wv16 = (f16*)(ws + 4 * SZ16 + 2 * WSZ);
  f16* wo16 = (f16*)(ws + 4 * SZ16 + 3 * WSZ);
  float* biasG = (float*)(ws + 4 * SZ16 + 4 * WSZ);  // 16*4352*4 B

  // wq pre-scaled by log2(e): QK^T scores land in the log2 domain.
  k_cvt<<<(MTOT * INNER / 4 + 255) / 256, 256, 0, stream>>>(hs, hs16, MTOT * INNER / 4, 1.0f);
  k_cvtw<<<dim3(INNER * D_MODEL / 4 / 256, 4), 256, 0, stream>>>(
      wq, wk, wv, wo, wq16, wk16, wv16, wo16);

  k_bias<<<dim3(BSTRIDE / 256, N_HEADS), 256, 0, stream>>>(relb, biasG);

  k_gemm_qkv<<<dim3(1536), 256, 0, stream>>>(
      hs16, wq16, wk16, wv16, q16, k16, vt16);

  k_attn<<<dim3(512), 512, 0, stream>>>(
      q16, k16, vt16, biasG, mask, hs16);

  k_gemm_out<<<dim3(512), 256, 0, stream>>>(
      hs16, wo16, (float*)d_out);
}

// Round 22
// 214.709 us; speedup vs baseline: 1.1225x; 1.0153x over previous
//
#include <hip/hip_runtime.h>
#include <cstdint>
#include <cstddef>

#define D_MODEL 1024
#define N_HEADS 16
#define INNER   1024
#define NBATCH  4
#define SEQ     2048
#define MTOT    (NBATCH * SEQ)   // 8192
#define LOG2E   1.44269504088896f
#define BSTRIDE 4352             // biasG per-head stride
#define MASKC   1442.695041f

typedef _Float16 f16;
typedef __attribute__((ext_vector_type(8))) _Float16 f16x8;
typedef __attribute__((ext_vector_type(4))) _Float16 f16x4;
typedef __attribute__((ext_vector_type(2))) _Float16 f16x2;
typedef __attribute__((ext_vector_type(2))) __fp16   h16x2;
typedef __attribute__((ext_vector_type(4))) float    f32x4;

// packed f32->f16 convert (RTZ) and dot2-accumulate shims
__device__ __forceinline__ f16x2 cvtpk(float x, float y) {
#if __has_builtin(__builtin_amdgcn_cvt_pkrtz)
  h16x2 r = __builtin_amdgcn_cvt_pkrtz(x, y);
  return __builtin_bit_cast(f16x2, r);
#else
  f16x2 r; r[0] = (f16)x; r[1] = (f16)y; return r;
#endif
}
__device__ __forceinline__ float dot2acc(f16x2 p, float acc) {
#if __has_builtin(__builtin_amdgcn_fdot2)
  h16x2 a = __builtin_bit_cast(h16x2, p);
  h16x2 one; one[0] = (__fp16)1.0f; one[1] = (__fp16)1.0f;
  return __builtin_amdgcn_fdot2(a, one, acc, false);
#else
  return acc + (float)p[0] + (float)p[1];
#endif
}

// ------------------------------------------------- fused prep kernel
// blocks [0,8192): hs f32->f16; [8192,12288): 4 weight converts (wq scaled);
// [12288,12560): T5 bias 1-D delta table (positions = arange -> rel = k-q).
__global__ void k_prep(const float* __restrict__ hs, const float* __restrict__ wq,
                       const float* __restrict__ wk, const float* __restrict__ wv,
                       const float* __restrict__ wo, const float* __restrict__ relb,
                       f16* __restrict__ hs16, f16* __restrict__ dq,
                       f16* __restrict__ dk, f16* __restrict__ dv,
                       f16* __restrict__ dwo, float* __restrict__ biasG) {
  const int blk = (int)blockIdx.x;
  if (blk < 8192) {
    const int i = blk * 256 + threadIdx.x;
    const float4 v = reinterpret_cast<const float4*>(hs)[i];
    f16x4 h;
    h[0] = (f16)v.x; h[1] = (f16)v.y; h[2] = (f16)v.z; h[3] = (f16)v.w;
    reinterpret_cast<f16x4*>(hs16)[i] = h;
  } else if (blk < 12288) {
    const int y = (blk - 8192) >> 10;          // 0..3, 1024 blocks each
    const int i = ((blk - 8192) & 1023) * 256 + threadIdx.x;
    const float* src = y == 0 ? wq : (y == 1 ? wk : (y == 2 ? wv : wo));
    f16* dst = y == 0 ? dq : (y == 1 ? dk : (y == 2 ? dv : dwo));
    const float scale = y == 0 ? LOG2E : 1.0f;
    const float4 v = reinterpret_cast<const float4*>(src)[i];
    f16x4 h;
    h[0] = (f16)(v.x * scale); h[1] = (f16)(v.y * scale);
    h[2] = (f16)(v.z * scale); h[3] = (f16)(v.w * scale);
    reinterpret_cast<f16x4*>(dst)[i] = h;
  } else {
    const int j = (blk - 12288) * 256 + threadIdx.x;  // 0..69631
    const int i = j % BSTRIDE;                         // 0..4351
    const int h = j / BSTRIDE;                         // 0..15
    if (h < N_HEADS) {
      const int d = i - 2048;
      const int sgn = d > 0 ? 16 : 0;
      const int a = d < 0 ? -d : d;
      int bucket;
      if (a < 8) {
        bucket = a;
      } else {
        float t = logf((float)a / 8.0f);
        t = t / 2.772588722239781f;   // ln(16)
        t = t * 8.0f;
        int lg = 8 + (int)t;
        bucket = lg < 15 ? lg : 15;
      }
      biasG[h * BSTRIDE + i] = relb[(sgn + bucket) * N_HEADS + h] * LOG2E - MASKC;
    }
  }
}

// ------------------------------------------------- async global->LDS (16B)
__device__ __forceinline__ void gload_lds16(const void* g, void* l) {
  __builtin_amdgcn_global_load_lds(
      (const __attribute__((address_space(1))) unsigned int*)g,
      (__attribute__((address_space(3))) unsigned int*)l,
      16, 0, 0);
}

// ------------------------------------------------- C = A * W^T  (f16 in, K=1024)
// MODE 0: f16 row-major; MODE 1: f32 row-major; MODE 2: Vt interleaved.
template <int MODE>
__device__ __forceinline__ void gemm_body(const f16* __restrict__ A,
                                          const f16* __restrict__ W,
                                          void* __restrict__ Cp,
                                          int m0, int n0) {
  __shared__ __align__(16) f16 As[128 * 64];
  __shared__ __align__(16) f16 Bs[128 * 64];
  const int t = threadIdx.x;
  const int lane = t & 63;
  const int wid = t >> 6;
  const int wr = wid >> 1;
  const int wc = wid & 1;
  const int g = lane >> 4;
  const int lr = lane & 15;

  f32x4 acc[4][4] = {};
  const char* Ab = (const char*)A;
  const char* Wb = (const char*)W;

  for (int kt = 0; kt < D_MODEL / 64; ++kt) {
    const int k0 = kt * 64;
    __syncthreads();
#pragma unroll
    for (int i = 0; i < 4; ++i) {
      const int idx = i * 256 + t;
      const int row = idx >> 3;
      const int cb  = (idx & 7) * 16;
      gload_lds16(Ab + ((size_t)(m0 + row) * D_MODEL + k0) * 2 + cb, (char*)As + idx * 16);
      gload_lds16(Wb + ((size_t)(n0 + row) * D_MODEL + k0) * 2 + cb, (char*)Bs + idx * 16);
    }
    asm volatile("s_waitcnt vmcnt(0)" ::: "memory");
    __syncthreads();

    f16x8 af[4][2], bf[4][2];
#pragma unroll
    for (int mi = 0; mi < 4; ++mi)
#pragma unroll
      for (int kk = 0; kk < 2; ++kk)
        af[mi][kk] = *(const f16x8*)&As[(wr * 64 + mi * 16 + lr) * 64 + kk * 32 + g * 8];
#pragma unroll
    for (int ni = 0; ni < 4; ++ni)
#pragma unroll
      for (int kk = 0; kk < 2; ++kk)
        bf[ni][kk] = *(const f16x8*)&Bs[(wc * 64 + ni * 16 + lr) * 64 + kk * 32 + g * 8];
#pragma unroll
    for (int kk = 0; kk < 2; ++kk)
#pragma unroll
      for (int mi = 0; mi < 4; ++mi)
#pragma unroll
        for (int ni = 0; ni < 4; ++ni)
          acc[mi][ni] = __builtin_amdgcn_mfma_f32_16x16x32_f16(af[mi][kk], bf[ni][kk], acc[mi][ni], 0, 0, 0);
  }

#pragma unroll
  for (int mi = 0; mi < 4; ++mi)
#pragma unroll
    for (int ni = 0; ni < 4; ++ni) {
      const int n = n0 + wc * 64 + ni * 16 + lr;
      if (MODE == 2) {
        const int mbase = m0 + wr * 64 + mi * 16 + g * 4;   // s2, multiple of 4
        const int b2 = mbase >> 11, s2 = mbase & (SEQ - 1);
        const int h2 = n >> 6, d2 = n & 63;
        const int sub = ((s2 & 15) >> 2) * 8 + ((s2 >> 4) & 1) * 4;
        f16x4 w;
#pragma unroll
        for (int r = 0; r < 4; ++r) w[r] = (f16)acc[mi][ni][r];
        *(f16x4*)((f16*)Cp + ((size_t)((b2 * 16 + h2) * 64 + d2) * SEQ + (s2 >> 5) * 32 + sub)) = w;
      } else {
#pragma unroll
        for (int r = 0; r < 4; ++r) {
          const int m = m0 + wr * 64 + mi * 16 + g * 4 + r;
          if (MODE == 1)
            ((float*)Cp)[(size_t)m * INNER + n] = acc[mi][ni][r];
          else
            ((f16*)Cp)[(size_t)m * INNER + n] = (f16)acc[mi][ni][r];
        }
      }
    }
}

// 1D grid 1536, XCD-swizzled: all 8 n-tiles of one (z,y) A-panel on one XCD.
__global__ __launch_bounds__(256) void k_gemm_qkv(
    const f16* __restrict__ A,
    const f16* __restrict__ Wq, const f16* __restrict__ Wk, const f16* __restrict__ Wv,
    f16* __restrict__ Cq, f16* __restrict__ Ck, f16* __restrict__ Vt) {
  const int bid = (int)blockIdx.x;
  const int X = bid & 7, l = bid >> 3;     // X = xcd, l = 0..191
  const int zy = X * 24 + (l >> 3);        // 0..191
  const int x = l & 7;
  const int z = zy >> 6, y = zy & 63;
  if (z == 0)      gemm_body<0>(A, Wq, Cq, y * 128, x * 128);
  else if (z == 1) gemm_body<0>(A, Wk, Ck, y * 128, x * 128);
  else             gemm_body<2>(A, Wv, Vt, y * 128, x * 128);
}

// 1D grid 512, XCD-swizzled similarly.
__global__ __launch_bounds__(256) void k_gemm_out(
    const f16* __restrict__ A, const f16* __restrict__ W, float* __restrict__ C) {
  const int bid = (int)blockIdx.x;
  const int X = bid & 7, l = bid >> 3;     // l 0..63
  const int y = X * 8 + (l >> 3), x = l & 7;
  gemm_body<1>(A, W, C, y * 128, x * 128);
}

// ------------------------------------------------- flash attention
// Round-21 (== round-16 perf, 107us): 8 waves x 32 q, one (b,h), KVBLK=32,
// 4-buffer counted-vmcnt pipeline (distance-2, vmcnt(1) before barrier),
// quad-parity bias, setprio, mask fast path.  launch_bounds(512,4) pins
// VGPR=64 -> 2-block/CU co-residency (r16 vs r19 A/B: 72+ VGPR serializes).
__global__ __launch_bounds__(512, 4) void k_attn(
    const f16* __restrict__ Q, const f16* __restrict__ K, const f16* __restrict__ Vt,
    const float* __restrict__ biasG, const float* __restrict__ mask,
    f16* __restrict__ ctx) {
  __shared__ __align__(16) float biasQ[4 * 2308]; // 4 parity copies, 36928 B
  __shared__ __align__(16) f16 Ks[4 * 2048];      // 4 bufs x 4KB, swz bits 4-6
  __shared__ __align__(16) f16 Vs[4 * 2048];      // 4 bufs x 4KB, swz bits 4-5
  __shared__ int mflag;

  // XCD-aware remap: all 8 q-chunks of one (b,h) on one XCD; 8 bh per XCD.
  const int nb = (int)blockIdx.x;
  const int v = (nb & 7) * 64 + (nb >> 3);
  const int bh = v >> 3, qc = v & 7;
  const int b = bh >> 4, h = bh & 15;

  const int t = threadIdx.x, lane = t & 63, wid = t >> 6;  // wid 0..7
  const int g = lane >> 4, lr = lane & 15;
  const int qb = qc * 256;

  const float* maskB = mask + (size_t)b * SEQ;
  {
    // window w[j] = biasG[h][2048 + (j - (qb+255))]; copy c slot m = w[4m+c ..+3]
    const float* bgh = biasG + (size_t)h * BSTRIDE + (1793 - qb);
    for (int idx = t; idx < 4 * 576; idx += 512) {
      const int c = idx / 576, m = idx - c * 576;
      const int src = 4 * m + c;
      float4 w;
      w.x = bgh[src]; w.y = bgh[src + 1]; w.z = bgh[src + 2]; w.w = bgh[src + 3];
      *(float4*)&biasQ[c * 2308 + 4 * m] = w;
    }
  }
  if (t == 0) mflag = 1;
  __syncthreads();
  {
    bool bad = false;
    for (int i = t; i < SEQ; i += 512) bad |= (maskB[i] != 1.0f);
    if (bad) mflag = 0;
  }

  const char* Kg = (const char*)K + ((size_t)(b * SEQ) * INNER + h * 64) * 2;
  const char* Vg = (const char*)Vt + ((size_t)bh * 64) * SEQ * 2;

  // staging roles (wave-uniform split): t<256 -> K chunk, t>=256 -> V chunk
  const bool isK = t < 256;
  const int ts = t & 255;
  const int krow = ts >> 3, kch = ts & 7;
  const int vrow = ts >> 2, vch = ts & 3;
  const int stsrc = isK ? ((kch * 16) ^ ((krow & 7) << 4))
                        : ((vch * 16) ^ ((vrow & 3) << 4));

  const int qw = qb + wid * 32;

  f16x8 qa[2][2];
#pragma unroll
  for (int hh = 0; hh < 2; ++hh)
#pragma unroll
    for (int kk = 0; kk < 2; ++kk)
      qa[hh][kk] = *(const f16x8*)&Q[(size_t)(b * SEQ + qw + hh * 16 + lr) * INNER + h * 64 + kk * 32 + g * 8];

  // hoisted per-lane LDS byte offsets (loop-invariant)
  int koffs[2][2], voffs[4];
#pragma unroll
  for (int s = 0; s < 2; ++s)
#pragma unroll
    for (int hf = 0; hf < 2; ++hf)
      koffs[s][hf] = (s * 16 + lr) * 128 + ((hf * 64 + g * 16) ^ ((lr & 7) << 4));
#pragma unroll
  for (int dn = 0; dn < 4; ++dn)
    voffs[dn] = (dn * 16 + lr) * 64 + ((g * 16) ^ ((lr & 3) << 4));

  f32x4 o[2][4] = {};
  float mrun[2] = {-__builtin_inff(), -__builtin_inff()};
  float lsum[2] = {0.0f, 0.0f};

  // quad-parity bias base: j0(K0) = K0 + jb2; quads at j0, j0+16, j0+32.
  const int jbase = 255 + 4 * g - wid * 32 - lr;
  const int jb2 = jbase - 16;
  const char* bqPtr = (const char*)biasQ
                      + (size_t)((jb2 & 3) * 2308 + ((jb2 >> 2) << 2)) * 4;

  // staging helper: stage 32-key tile with key base KB into buffer WB
#define STAGE(WB, KB)                                                          \
  {                                                                            \
    if (isK)                                                                   \
      gload_lds16(Kg + ((size_t)((KB) + krow) * INNER) * 2 + stsrc,            \
                  (char*)Ks + (WB) * 4096 + ts * 16);                          \
    else                                                                       \
      gload_lds16(Vg + ((size_t)vrow * SEQ + (KB)) * 2 + stsrc,                \
                  (char*)Vs + (WB) * 4096 + ts * 16);                          \
  }

  // prologue: stage tiles 0 and 1; wait for tile 0 (1 load may stay in flight)
  STAGE(0, 0)
  STAGE(1, 32)
  asm volatile("s_waitcnt vmcnt(1)" ::: "memory");
  __syncthreads();
  const bool useMask = (mflag == 0);

#define ATTN_ITER(BUF, K0, MK)                                                 \
  {                                                                            \
    float4 mk0 = {}, mk1 = {};                                                 \
    if (MK) {                                                                  \
      mk0 = *(const float4*)(maskB + (K0) + 4 * g);                            \
      mk1 = *(const float4*)(maskB + (K0) + 16 + 4 * g);                       \
    }                                                                          \
    const int kst_ = ((K0) + 64 < SEQ) ? (K0) + 64 : 0;                        \
    STAGE(((BUF) + 2) & 3, kst_)                                               \
    const f32x4 bq0 = *(const f32x4*)(bqPtr + (K0) * 4);                       \
    const f32x4 bq1 = *(const f32x4*)(bqPtr + (K0) * 4 + 64);                  \
    const f32x4 bq2 = *(const f32x4*)(bqPtr + (K0) * 4 + 128);                 \
    f16x8 kf[2][2];                                                            \
    _Pragma("unroll") for (int s = 0; s < 2; ++s)                              \
      _Pragma("unroll") for (int hf = 0; hf < 2; ++hf)                         \
        kf[s][hf] = *(const f16x8*)((const char*)Ks + (BUF) * 4096 + koffs[s][hf]); \
    f16x8 vv[4];                                                               \
    _Pragma("unroll") for (int dn = 0; dn < 4; ++dn)                           \
      vv[dn] = *(const f16x8*)((const char*)Vs + (BUF) * 4096 + voffs[dn]);    \
    f32x4 sg[2][2];                                                            \
    __builtin_amdgcn_s_setprio(1);                                             \
    _Pragma("unroll") for (int hh = 0; hh < 2; ++hh)                           \
      _Pragma("unroll") for (int s = 0; s < 2; ++s) {                          \
        const f32x4 bq = hh ? (s ? bq1 : bq0) : (s ? bq2 : bq1);               \
        f32x4 z;                                                               \
        if (MK) {                                                              \
          const float* mkp = (s == 0) ? (const float*)&mk0 : (const float*)&mk1; \
          _Pragma("unroll") for (int r = 0; r < 4; ++r)                        \
            z[r] = fmaf(mkp[r], MASKC, bq[r]);                                 \
        } else {                                                               \
          z = bq;                                                              \
        }                                                                      \
        z = __builtin_amdgcn_mfma_f32_16x16x32_f16(kf[s][0], qa[hh][0], z, 0, 0, 0); \
        z = __builtin_amdgcn_mfma_f32_16x16x32_f16(kf[s][1], qa[hh][1], z, 0, 0, 0); \
        sg[hh][s] = z;                                                         \
      }                                                                        \
    __builtin_amdgcn_s_setprio(0);                                             \
    float mxA = fmaxf(fmaxf(fmaxf(sg[0][0][0], sg[0][0][1]), fmaxf(sg[0][0][2], sg[0][0][3])), \
                      fmaxf(fmaxf(sg[0][1][0], sg[0][1][1]), fmaxf(sg[0][1][2], sg[0][1][3]))); \
    float mxB = fmaxf(fmaxf(fmaxf(sg[1][0][0], sg[1][0][1]), fmaxf(sg[1][0][2], sg[1][0][3])), \
                      fmaxf(fmaxf(sg[1][1][0], sg[1][1][1]), fmaxf(sg[1][1][2], sg[1][1][3]))); \
    if (__any((mxA > mrun[0] + 11.5415603f) || (mxB > mrun[1] + 11.5415603f))) { \
      mxA = fmaxf(mxA, __shfl_xor(mxA, 16));                                   \
      mxB = fmaxf(mxB, __shfl_xor(mxB, 16));                                   \
      mxA = fmaxf(mxA, __shfl_xor(mxA, 32));                                   \
      mxB = fmaxf(mxB, __shfl_xor(mxB, 32));                                   \
      const float mnA = fmaxf(mrun[0], mxA), mnB = fmaxf(mrun[1], mxB);        \
      const float aA = __builtin_amdgcn_exp2f(mrun[0] - mnA);                  \
      const float aB = __builtin_amdgcn_exp2f(mrun[1] - mnB);                  \
      lsum[0] *= aA; lsum[1] *= aB;                                            \
      _Pragma("unroll") for (int dn = 0; dn < 4; ++dn)                         \
        _Pragma("unroll") for (int r = 0; r < 4; ++r) {                        \
          o[0][dn][r] *= aA; o[1][dn][r] *= aB;                                \
        }                                                                      \
      mrun[0] = mnA; mrun[1] = mnB;                                            \
    }                                                                          \
    f16x8 pfA8, pfB8;                                                          \
    _Pragma("unroll") for (int s = 0; s < 2; ++s) {                            \
      float eA[4], eB[4];                                                      \
      _Pragma("unroll") for (int r = 0; r < 4; ++r) {                          \
        eA[r] = __builtin_amdgcn_exp2f(sg[0][s][r] - mrun[0]);                 \
        eB[r] = __builtin_amdgcn_exp2f(sg[1][s][r] - mrun[1]);                 \
      }                                                                        \
      const f16x2 a0 = cvtpk(eA[0], eA[1]), a1 = cvtpk(eA[2], eA[3]);          \
      const f16x2 b0 = cvtpk(eB[0], eB[1]), b1 = cvtpk(eB[2], eB[3]);          \
      lsum[0] = dot2acc(a0, lsum[0]); lsum[0] = dot2acc(a1, lsum[0]);          \
      lsum[1] = dot2acc(b0, lsum[1]); lsum[1] = dot2acc(b1, lsum[1]);          \
      pfA8[s * 4 + 0] = a0[0]; pfA8[s * 4 + 1] = a0[1];                        \
      pfA8[s * 4 + 2] = a1[0]; pfA8[s * 4 + 3] = a1[1];                        \
      pfB8[s * 4 + 0] = b0[0]; pfB8[s * 4 + 1] = b0[1];                        \
      pfB8[s * 4 + 2] = b1[0]; pfB8[s * 4 + 3] = b1[1];                        \
    }                                                                          \
    __builtin_amdgcn_s_setprio(1);                                             \
    _Pragma("unroll") for (int dn = 0; dn < 4; ++dn) {                         \
      o[0][dn] = __builtin_amdgcn_mfma_f32_16x16x32_f16(vv[dn], pfA8, o[0][dn], 0, 0, 0); \
      o[1][dn] = __builtin_amdgcn_mfma_f32_16x16x32_f16(vv[dn], pfB8, o[1][dn], 0, 0, 0); \
    }                                                                          \
    __builtin_amdgcn_s_setprio(0);                                             \
    asm volatile("s_waitcnt vmcnt(1)" ::: "memory");                           \
    __syncthreads();                                                           \
  }

  if (useMask) {
    for (int k0 = 0; k0 < SEQ; k0 += 128) {
      ATTN_ITER(0, k0, 1)
      ATTN_ITER(1, k0 + 32, 1)
      ATTN_ITER(2, k0 + 64, 1)
      ATTN_ITER(3, k0 + 96, 1)
    }
  } else {
    for (int k0 = 0; k0 < SEQ; k0 += 128) {
      ATTN_ITER(0, k0, 0)
      ATTN_ITER(1, k0 + 32, 0)
      ATTN_ITER(2, k0 + 64, 0)
      ATTN_ITER(3, k0 + 96, 0)
    }
  }

  // epilogue: reduce per-lane partial sums across the 4 g-groups of each row
  lsum[0] += __shfl_xor(lsum[0], 16);
  lsum[1] += __shfl_xor(lsum[1], 16);
  lsum[0] += __shfl_xor(lsum[0], 32);
  lsum[1] += __shfl_xor(lsum[1], 32);

  const float invA = 1.0f / lsum[0], invB = 1.0f / lsum[1];
#pragma unroll
  for (int dn = 0; dn < 4; ++dn) {
    f16x4 wA, wB;
#pragma unroll
    for (int r = 0; r < 4; ++r) {
      wA[r] = (f16)(o[0][dn][r] * invA);
      wB[r] = (f16)(o[1][dn][r] * invB);
    }
    *(f16x4*)&ctx[(size_t)(b * SEQ + qw + lr) * INNER + h * 64 + dn * 16 + 4 * g] = wA;
    *(f16x4*)&ctx[(size_t)(b * SEQ + qw + 16 + lr) * INNER + h * 64 + dn * 16 + 4 * g] = wB;
  }
}

// ----------------------------------------------------------------- launch
extern "C" void kernel_launch(void* const* d_in, const int* in_sizes, int n_in,
                              void* d_out, int out_size, void* d_ws, size_t ws_size,
                              hipStream_t stream) {
  const float* hs   = (const float*)d_in[0];
  const float* mask = (const float*)d_in[2];
  const float* wq   = (const float*)d_in[3];
  const float* wk   = (const float*)d_in[4];
  const float* wv   = (const float*)d_in[5];
  const float* wo   = (const float*)d_in[6];
  const float* relb = (const float*)d_in[7];

  char* ws = (char*)d_ws;
  const size_t SZ16 = (size_t)MTOT * INNER * 2;      // 16 MiB
  const size_t WSZ  = (size_t)INNER * D_MODEL * 2;   // 2 MiB
  f16* hs16 = (f16*)(ws);                            // reused as ctx16 after QKV
  f16* q16  = (f16*)(ws + SZ16);
  f16* k16  = (f16*)(ws + 2 * SZ16);
  f16* vt16 = (f16*)(ws + 3 * SZ16);                 // V transposed+interleaved
  f16* wq16 = (f16*)(ws + 4 * SZ16);
  f16* wk16 = (f16*)(ws + 4 * SZ16 + WSZ);
  f16* wv16 = (f16*)(ws + 4 * SZ16 + 2 * WSZ);
  f16* wo16 = (f16*)(ws + 4 * SZ16 + 3 * WSZ);
  float* biasG = (float*)(ws + 4 * SZ16 + 4 * WSZ);  // 16*4352*4 B

  // fused prep: hs cvt + 4 weight cvts (wq pre-scaled by log2e) + bias table
  k_prep<<<dim3(8192 + 4096 + (BSTRIDE * N_HEADS + 255) / 256), 256, 0, stream>>>(
      hs, wq, wk, wv, wo, relb, hs16, wq16, wk16, wv16, wo16, biasG);

  k_gemm_qkv<<<dim3(1536), 256, 0, stream>>>(
      hs16, wq16, wk16, wv16, q16, k16, vt16);

  k_attn<<<dim3(512), 512, 0, stream>>>(
      q16, k16, vt16, biasG, mask, hs16);

  k_gemm_out<<<dim3(512), 256, 0, stream>>>(
      hs16, wo16, (float*)d_out);
}